// Round 14
// baseline (1118.867 us; speedup 1.0000x reference)
//
#include <hip/hip_runtime.h>
#include <math.h>

#define C_RES 0.89442719f
#define C_NEW 0.4472f
#define LN_EPS 1e-5f
#define BESSEL_PREF 0.6324555320336759f  // sqrt(2/5)
#define RC_INV 0.2f

typedef __attribute__((ext_vector_type(8))) short short8;
typedef __attribute__((ext_vector_type(8))) unsigned short u16x8;
typedef __attribute__((ext_vector_type(16))) float f32x16;

// Pade(5,2)-style continued-fraction tanh, input clamped to [-3,3].
__device__ __forceinline__ float fast_tanh(float x) {
  float t = fminf(3.0f, fmaxf(-3.0f, x));
  float t2 = t * t;
  float num = t * fmaf(t2, 10.0f, 105.0f);
  float den = fmaf(t2, fmaf(t2, 1.0f, 45.0f), 105.0f);
  return num * __builtin_amdgcn_rcpf(den);
}

// compiler bf16 cast (RNE) -> hipcc fuses pairs into v_cvt_pk_bf16_f32
__device__ __forceinline__ unsigned short f2b(float f) {
  __bf16 h = (__bf16)f;
  return __builtin_bit_cast(unsigned short, h);
}

__device__ __forceinline__ float b2f(unsigned short v) {
  return __uint_as_float((unsigned)v << 16);
}

__device__ __forceinline__ u16x8 cvt8(const float* s) {
  const float4 v0 = *(const float4*)s;
  const float4 v1 = *(const float4*)(s + 4);
  u16x8 w;
  w[0]=f2b(v0.x); w[1]=f2b(v0.y); w[2]=f2b(v0.z); w[3]=f2b(v0.w);
  w[4]=f2b(v1.x); w[5]=f2b(v1.y); w[6]=f2b(v1.z); w[7]=f2b(v1.w);
  return w;
}

__device__ __forceinline__ short8 cvt8s(const float* s) {
  const float4 v0 = *(const float4*)s;
  const float4 v1 = *(const float4*)(s + 4);
  short8 w;
  w[0]=(short)f2b(v0.x); w[1]=(short)f2b(v0.y); w[2]=(short)f2b(v0.z); w[3]=(short)f2b(v0.w);
  w[4]=(short)f2b(v1.x); w[5]=(short)f2b(v1.y); w[6]=(short)f2b(v1.z); w[7]=(short)f2b(v1.w);
  return w;
}

__device__ __forceinline__ float poly_cutoff(float x) {
  float xr = x * RC_INV;
  if (xr >= 1.0f) return 0.0f;
  float x2 = xr * xr;
  float x3 = x2 * xr;
  float x6 = x3 * x3;
  return 1.0f - 28.0f * x6 + 48.0f * x6 * xr - 21.0f * x6 * x2;
}

// A-frag slot swizzle.
__device__ __forceinline__ int swz(int s, int kc) {
  return s ^ ((s >> 5) << 1) ^ ((kc & 1) << 2);
}

__global__ void zero_int_kernel(int* __restrict__ p, int n) {
  int i = blockIdx.x * blockDim.x + threadIdx.x;
  int stride = gridDim.x * blockDim.x;
  for (; i < n; i += stride) p[i] = 0;
}

// ---------------- CSR build: hist -> scan -> scatter --------------------------

__global__ void hist_kernel(int E, const int* __restrict__ idx, int* __restrict__ ecnt) {
  int t = blockIdx.x * 256 + threadIdx.x;
  if (t < E) atomicAdd(&ecnt[idx[E + t]], 1);
}

__launch_bounds__(1024)
__global__ void scan_kernel(const int* __restrict__ ecnt, int* __restrict__ eoff,
                            int* __restrict__ ecur, int n) {
  __shared__ int wsum[16];
  __shared__ int carry;
  const int tid = threadIdx.x;
  const int lane = tid & 63, wid = tid >> 6;
  if (tid == 0) carry = 0;
  __syncthreads();
  for (int b0 = 0; b0 < n; b0 += 1024) {
    const int i = b0 + tid;
    const int v = (i < n) ? ecnt[i] : 0;
    int incl = v;
    #pragma unroll
    for (int o = 1; o < 64; o <<= 1) {
      const int t = __shfl_up(incl, o);
      if (lane >= o) incl += t;
    }
    if (lane == 63) wsum[wid] = incl;
    __syncthreads();
    if (wid == 0) {
      const int wv = (lane < 16) ? wsum[lane] : 0;
      int wsc = wv;
      #pragma unroll
      for (int o = 1; o < 16; o <<= 1) {
        const int t = __shfl_up(wsc, o);
        if (lane >= o) wsc += t;
      }
      if (lane < 16) wsum[lane] = wsc - wv;  // exclusive
    }
    __syncthreads();
    const int c0 = carry;
    const int excl = c0 + wsum[wid] + incl - v;
    if (i < n) { eoff[i] = excl; ecur[i] = excl; }
    __syncthreads();
    if (tid == 1023) carry = c0 + wsum[15] + incl;
    __syncthreads();
  }
  if (tid == 0) eoff[n] = carry;
}

__global__ void scatter_kernel(int E, const int* __restrict__ idx,
                               int* __restrict__ ecur, int* __restrict__ perm) {
  int t = blockIdx.x * 256 + threadIdx.x;
  if (t < E) {
    const int pos = atomicAdd(&ecur[idx[E + t]], 1);
    perm[pos] = t;
  }
}

// ---------------- weight packers ---------------------------------------------

__global__ void pack_hid_weights(const float* __restrict__ W1,
                                 const float* __restrict__ W2,
                                 const float* __restrict__ W3,
                                 unsigned short* __restrict__ out)
{
  int t = blockIdx.x * 256 + threadIdx.x;  // 0..131071
  if (t >= 131072) return;
  int l = t >> 16;
  int oidx = t & 65535;
  const float* src;
  int midx;
  if (oidx < 32768)      { src = W1 + l * 32768; midx = oidx; }
  else if (oidx < 49152) { src = W2 + l * 16384; midx = oidx - 32768; }
  else                   { src = W3 + l * 16384; midx = oidx - 49152; }
  int j = midx & 7;
  int lane = (midx >> 3) & 63;
  int blk = midx >> 9;
  int ct = blk & 3, kc = blk >> 2;
  int col = ct * 32 + (lane & 31);
  int k = kc * 16 + (lane >> 5) * 8 + j;
  out[l * 65536 + oidx] = f2b(src[k * 128 + col]);
}

__global__ void pack_rdl_weights(const float* __restrict__ W1,
                                 const float* __restrict__ W2,
                                 const float* __restrict__ W3,
                                 unsigned short* __restrict__ out)
{
  int t = blockIdx.x * 256 + threadIdx.x;  // 0..40959
  if (t >= 40960) return;
  int l = t / 20480;
  int o = t - l * 20480;
  const float* src;
  int midx;
  if (o < 12288)      { src = W1 + l * 12288; midx = o; }
  else if (o < 16384) { src = W2 + l * 4096;  midx = o - 12288; }
  else                { src = W3 + l * 4096;  midx = o - 16384; }
  int j = midx & 7;
  int lane = (midx >> 3) & 63;
  int blk = midx >> 9;
  int ct = blk & 1, kc = blk >> 1;
  int col = ct * 32 + (lane & 31);
  int k = kc * 16 + (lane >> 5) * 8 + j;
  out[l * 20480 + o] = f2b(src[k * 64 + col]);
}

__global__ void pack_feat_weights(const float* __restrict__ rdW1,
                                  const float* __restrict__ rdW2,
                                  const float* __restrict__ rdW3,
                                  const float* __restrict__ srW1,
                                  const float* __restrict__ srW2,
                                  const float* __restrict__ srW3,
                                  unsigned short* __restrict__ out)
{
  int t = blockIdx.x * 256 + threadIdx.x;  // 0..18431
  if (t >= 18432) return;
  const int blk = t >> 9, midx = t & 511;
  const int j = midx & 7, lane = (midx >> 3) & 63;
  const float* src; int kc, ct, K, NC;
  if (blk < 4)       { int b = blk;      src = rdW1; kc = b>>1; ct = b&1; K = 24; NC = 64; }
  else if (blk < 12) { int b = blk - 4;  src = rdW2; kc = b>>1; ct = b&1; K = 64; NC = 64; }
  else if (blk < 20) { int b = blk - 12; src = rdW3; kc = b>>1; ct = b&1; K = 64; NC = 64; }
  else if (blk < 24) { int b = blk - 20; src = srW1; kc = b>>1; ct = b&1; K = 24; NC = 64; }
  else if (blk < 32) { int b = blk - 24; src = srW2; kc = b>>1; ct = b&1; K = 64; NC = 64; }
  else               { int b = blk - 32; src = srW3; kc = b;    ct = 0;   K = 64; NC = 16; }
  const int col = ct * 32 + (lane & 31);
  const int k = kc * 16 + (lane >> 5) * 8 + j;
  const float v = (k < K && col < NC) ? src[k * NC + col] : 0.0f;
  out[t] = f2b(v);
}

__global__ void pack_emb_weights(const float* __restrict__ W,
                                 unsigned short* __restrict__ out)
{
  int t = blockIdx.x * 256 + threadIdx.x;  // 0..8191
  if (t >= 8192) return;
  const int j = t & 7, lane = (t >> 3) & 63, blk = t >> 9;
  const int ct = blk & 3, kc = blk >> 2;
  const int col = ct * 32 + (lane & 31);
  const int k = kc * 16 + (lane >> 5) * 8 + j;
  out[t] = f2b(W[k * 128 + col]);
}

// ---------------- stage-A via bf16 MFMA (merged E|E2) ------------------------
// 96 rows/block, 192 threads (3 waves), one barrier.

#define FEAT_TRANS(BASEBLK, V0, V1) do {                                        \
    _Pragma("unroll")                                                           \
    for (int ct_ = 0; ct_ < 2; ++ct_) {                                         \
      const int colh_ = ct_*32 + cl;                                            \
      const int kc2_  = colh_ >> 4;                                             \
      const int b3_   = (colh_ >> 3) & 1;                                       \
      const int jj_   = colh_ & 7;                                              \
      const int blk_  = ((BASEBLK) + kc2_*3 + wave)*512;                        \
      _Pragma("unroll")                                                         \
      for (int q_ = 0; q_ < 16; ++q_) {                                         \
        const int row32_ = (q_ & 3) + 8*(q_ >> 2) + 4*(lane >> 5);              \
        const int s2_ = (row32_ & 31) + 32*b3_;                                 \
        const float v_ = ct_ ? (V1)[q_] : (V0)[q_];                             \
        afrag[blk_ + swz(s2_, kc2_)*8 + jj_] = f2b(fast_tanh(v_));              \
      }                                                                         \
    }                                                                           \
  } while (0)

__launch_bounds__(192)
__global__ void feat_mfma(
    int g1, int n1, const float* __restrict__ lens1, const int* __restrict__ idx1,
    float* __restrict__ radial1, float* __restrict__ ud1,
    int n2, const float* __restrict__ lens2, const int* __restrict__ idx2,
    float* __restrict__ radial2, float* __restrict__ ud2,
    const int* __restrict__ types, const float* __restrict__ vecs,
    const float* __restrict__ bessel_w,
    const unsigned short* __restrict__ wpackf,
    const float* __restrict__ srb1, const float* __restrict__ srb2,
    const float* __restrict__ srb3,
    const float* __restrict__ rdb1, const float* __restrict__ rdb2,
    const float* __restrict__ rdb3,
    const float* __restrict__ eln_g, const float* __restrict__ eln_b,
    float* __restrict__ msgbuf)
{
  __shared__ __align__(16) unsigned short afrag[30*512];  // 30KB
  __shared__ __align__(16) unsigned short wlds[36*512];   // 36KB
  __shared__ float udl[96];

  const int tid  = threadIdx.x;    // 0..191
  const int lane = tid & 63;
  const int wave = tid >> 6;
  const int cl   = lane & 31;

  int blk = blockIdx.x;
  const bool has_sr = (blk < g1);
  int nrows; const float* lens; const int* idx; float* radial_out; float* ud_out;
  if (has_sr) { nrows = n1; lens = lens1; idx = idx1; radial_out = radial1; ud_out = ud1; }
  else { blk -= g1; nrows = n2; lens = lens2; idx = idx2; radial_out = radial2; ud_out = ud2; }
  const int base = blk * 96;

  for (int i = tid; i < 2304; i += 192)
    *(u16x8*)&wlds[i*8] = *(const u16x8*)&wpackf[i*8];

  {
    const int r = tid >> 1, h = tid & 1;
    int rowc = base + r;
    const bool valid = rowc < nrows;
    if (!valid) rowc = nrows - 1;
    const int i0 = idx[rowc];
    const int i1 = idx[nrows + rowc];
    const float len = lens[rowc];
    const float ud = poly_cutoff(len);
    const int t0 = types[i0], t1 = types[i1];
    const float invl = 1.0f / len;
    const int rt = r >> 5;
    #pragma unroll
    for (int m = 0; m < 12; ++m) {
      const int k = h + m*2;
      float v;
      if (k < 4)      v = (t0 == k) ? 1.0f : 0.0f;
      else if (k < 8) v = (t1 == (k-4)) ? 1.0f : 0.0f;
      else            v = ud * BESSEL_PREF * __sinf(bessel_w[k-8] * len * RC_INV) * invl;
      const int kc = k >> 4;
      const int s_ = (r & 31) + 32*((k >> 3) & 1);
      afrag[(kc*3 + rt)*512 + swz(s_, kc)*8 + (k & 7)] = f2b(v);
    }
    #pragma unroll
    for (int m = 0; m < 4; ++m) {
      const int k = 24 + h + m*2;
      const int s_ = (r & 31) + 32*((k >> 3) & 1);
      afrag[(1*3 + rt)*512 + swz(s_, 1)*8 + (k & 7)] = 0;
    }
    if (h == 0) {
      udl[r] = ud;
      if (valid) {
        ud_out[rowc] = ud;
        if (has_sr) {
          msgbuf[(size_t)rowc*20 + 16] = ud * vecs[(size_t)rowc*3 + 0];
          msgbuf[(size_t)rowc*20 + 17] = ud * vecs[(size_t)rowc*3 + 1];
          msgbuf[(size_t)rowc*20 + 18] = ud * vecs[(size_t)rowc*3 + 2];
        }
      }
    }
  }
  __syncthreads();

  f32x16 acc0, acc1;

  // ======== rd path ========
  {
    const float bv0 = rdb1[cl], bv1 = rdb1[32 + cl];
    #pragma unroll
    for (int q = 0; q < 16; ++q) { acc0[q] = bv0; acc1[q] = bv1; }
  }
  #pragma unroll
  for (int kc = 0; kc < 2; ++kc) {
    const short8 a  = *(const short8*)&afrag[(kc*3 + wave)*512 + swz(lane, kc)*8];
    const short8 w0 = *(const short8*)&wlds[(kc*2 + 0)*512 + lane*8];
    const short8 w1 = *(const short8*)&wlds[(kc*2 + 1)*512 + lane*8];
    acc0 = __builtin_amdgcn_mfma_f32_32x32x16_bf16(a, w0, acc0, 0, 0, 0);
    acc1 = __builtin_amdgcn_mfma_f32_32x32x16_bf16(a, w1, acc1, 0, 0, 0);
  }
  FEAT_TRANS(6, acc0, acc1);

  {
    const float bv0 = rdb2[cl], bv1 = rdb2[32 + cl];
    #pragma unroll
    for (int q = 0; q < 16; ++q) { acc0[q] = bv0; acc1[q] = bv1; }
  }
  #pragma unroll
  for (int kc = 0; kc < 4; ++kc) {
    const short8 a  = *(const short8*)&afrag[((6 + kc*3) + wave)*512 + swz(lane, kc)*8];
    const short8 w0 = *(const short8*)&wlds[(4 + kc*2 + 0)*512 + lane*8];
    const short8 w1 = *(const short8*)&wlds[(4 + kc*2 + 1)*512 + lane*8];
    acc0 = __builtin_amdgcn_mfma_f32_32x32x16_bf16(a, w0, acc0, 0, 0, 0);
    acc1 = __builtin_amdgcn_mfma_f32_32x32x16_bf16(a, w1, acc1, 0, 0, 0);
  }
  FEAT_TRANS(18, acc0, acc1);

  {
    const float bv0 = rdb3[cl], bv1 = rdb3[32 + cl];
    #pragma unroll
    for (int q = 0; q < 16; ++q) { acc0[q] = bv0; acc1[q] = bv1; }
  }
  #pragma unroll
  for (int kc = 0; kc < 4; ++kc) {
    const short8 a  = *(const short8*)&afrag[((18 + kc*3) + wave)*512 + swz(lane, kc)*8];
    const short8 w0 = *(const short8*)&wlds[(12 + kc*2 + 0)*512 + lane*8];
    const short8 w1 = *(const short8*)&wlds[(12 + kc*2 + 1)*512 + lane*8];
    acc0 = __builtin_amdgcn_mfma_f32_32x32x16_bf16(a, w0, acc0, 0, 0, 0);
    acc1 = __builtin_amdgcn_mfma_f32_32x32x16_bf16(a, w1, acc1, 0, 0, 0);
  }
  {
    const float eg0 = eln_g[cl],      eb0 = eln_b[cl];
    const float eg1 = eln_g[32 + cl], eb1 = eln_b[32 + cl];
    #pragma unroll
    for (int q = 0; q < 16; ++q) {
      const float v0 = acc0[q], v1 = acc1[q];
      float s = v0 + v1, ss = v0*v0 + v1*v1;
      #pragma unroll
      for (int o = 1; o <= 16; o <<= 1) {
        s  += __shfl_xor(s, o);
        ss += __shfl_xor(ss, o);
      }
      const float m   = s * (1.0f/64.0f);
      const float inv = rsqrtf(ss * (1.0f/64.0f) - m*m + LN_EPS);
      const int row32 = (q & 3) + 8*(q >> 2) + 4*(lane >> 5);
      const int rloc  = wave*32 + row32;
      const int row   = base + rloc;
      if (row < nrows) {
        const float u = udl[rloc];
        radial_out[(size_t)row*64 + cl]      = ((v0 - m)*inv*eg0 + eb0) * u;
        radial_out[(size_t)row*64 + 32 + cl] = ((v1 - m)*inv*eg1 + eb1) * u;
      }
    }
  }

  // ======== sr path ========
  if (has_sr) {
    {
      const float bv0 = srb1[cl], bv1 = srb1[32 + cl];
      #pragma unroll
      for (int q = 0; q < 16; ++q) { acc0[q] = bv0; acc1[q] = bv1; }
    }
    #pragma unroll
    for (int kc = 0; kc < 2; ++kc) {
      const short8 a  = *(const short8*)&afrag[(kc*3 + wave)*512 + swz(lane, kc)*8];
      const short8 w0 = *(const short8*)&wlds[(20 + kc*2 + 0)*512 + lane*8];
      const short8 w1 = *(const short8*)&wlds[(20 + kc*2 + 1)*512 + lane*8];
      acc0 = __builtin_amdgcn_mfma_f32_32x32x16_bf16(a, w0, acc0, 0, 0, 0);
      acc1 = __builtin_amdgcn_mfma_f32_32x32x16_bf16(a, w1, acc1, 0, 0, 0);
    }
    FEAT_TRANS(6, acc0, acc1);

    {
      const float bv0 = srb2[cl], bv1 = srb2[32 + cl];
      #pragma unroll
      for (int q = 0; q < 16; ++q) { acc0[q] = bv0; acc1[q] = bv1; }
    }
    #pragma unroll
    for (int kc = 0; kc < 4; ++kc) {
      const short8 a  = *(const short8*)&afrag[((6 + kc*3) + wave)*512 + swz(lane, kc)*8];
      const short8 w0 = *(const short8*)&wlds[(24 + kc*2 + 0)*512 + lane*8];
      const short8 w1 = *(const short8*)&wlds[(24 + kc*2 + 1)*512 + lane*8];
      acc0 = __builtin_amdgcn_mfma_f32_32x32x16_bf16(a, w0, acc0, 0, 0, 0);
      acc1 = __builtin_amdgcn_mfma_f32_32x32x16_bf16(a, w1, acc1, 0, 0, 0);
    }
    FEAT_TRANS(18, acc0, acc1);

    {
      const float bv0 = (cl < 16) ? srb3[cl] : 0.0f;
      #pragma unroll
      for (int q = 0; q < 16; ++q) acc0[q] = bv0;
    }
    #pragma unroll
    for (int kc = 0; kc < 4; ++kc) {
      const short8 a  = *(const short8*)&afrag[((18 + kc*3) + wave)*512 + swz(lane, kc)*8];
      const short8 w0 = *(const short8*)&wlds[(32 + kc)*512 + lane*8];
      acc0 = __builtin_amdgcn_mfma_f32_32x32x16_bf16(a, w0, acc0, 0, 0, 0);
    }
    if (cl < 16) {
      #pragma unroll
      for (int q = 0; q < 16; ++q) {
        const int row32 = (q & 3) + 8*(q >> 2) + 4*(lane >> 5);
        const int rloc  = wave*32 + row32;
        const int row   = base + rloc;
        if (row < nrows) msgbuf[(size_t)row*20 + cl] = acc0[q] * udl[rloc];
      }
    }
  }
}

// ---------------- SE(2) message gather: aggS (no atomics) --------------------

__launch_bounds__(256)
__global__ void msg_gather_kernel(int N, const int* __restrict__ eoff,
                                  const int* __restrict__ perm,
                                  const float* __restrict__ msgbuf,
                                  float* __restrict__ aggS)
{
  const int w = (blockIdx.x * 256 + threadIdx.x) >> 6;
  const int lane = threadIdx.x & 63;
  if (w >= N) return;
  const int s = eoff[w], e = eoff[w + 1];
  const int d = lane / 3, c = lane - d * 3;
  float acc = 0.0f;
  for (int j = s; j < e; ++j) {
    const int ed = perm[j];
    if (lane < 48)
      acc += msgbuf[(size_t)ed*20 + d] * msgbuf[(size_t)ed*20 + 16 + c];
  }
  if (lane < 48) aggS[(size_t)w*48 + lane] = acc;
}

// ---------------- node embedding (gram + LN) ---------------------------------

__device__ __forceinline__ void block128_stats(float x, float& m, float& inv, float* red) {
  float s = x, ss = x*x;
  #pragma unroll
  for (int o = 32; o; o >>= 1) { s += __shfl_down(s, o); ss += __shfl_down(ss, o); }
  const int t = threadIdx.x;
  if ((t & 63) == 0) { red[(t >> 6)*2] = s; red[(t >> 6)*2 + 1] = ss; }
  __syncthreads();
  const float S = red[0] + red[2], SS = red[1] + red[3];
  m = S * (1.0f/128.0f);
  const float var = SS * (1.0f/128.0f) - m*m;
  inv = rsqrtf(var + LN_EPS);
}

__launch_bounds__(128)
__global__ void node_emb_kernel(int N, const float* __restrict__ aggS,
                                const int* __restrict__ ecnt,
                                const float* __restrict__ g, const float* __restrict__ b,
                                float* __restrict__ node_emb)
{
  const int n = blockIdx.x, t = threadIdx.x;
  __shared__ float S[48];
  __shared__ float red[4];
  if (t < 48) S[t] = aggS[(size_t)n*48 + t];
  __syncthreads();
  const float ic = 1.0f / fmaxf((float)ecnt[n], 1.0f);
  const int d = t >> 3, e = t & 7;
  const float x = (S[d*3+0]*S[e*3+0] + S[d*3+1]*S[e*3+1] + S[d*3+2]*S[e*3+2]) * ic * ic;
  float m, inv;
  block128_stats(x, m, inv, red);
  node_emb[(size_t)n*128 + t] = (x - m)*inv*g[t] + b[t];
}

// ---------------- per-layer aggregation: CSR gather (no atomics) -------------

__launch_bounds__(256)
__global__ void agg_gather_kernel(int N, const int* __restrict__ eoff,
                                  const int* __restrict__ perm,
                                  const float* __restrict__ radial,
                                  float* __restrict__ mean_r)
{
  const int w = (blockIdx.x * 256 + threadIdx.x) >> 6;
  const int lane = threadIdx.x & 63;
  if (w >= N) return;
  const int s = eoff[w], e = eoff[w + 1];
  float acc = 0.0f;
  for (int j = s; j < e; ++j) {
    const int ed = perm[j];
    acc += radial[(size_t)ed * 64 + lane];
  }
  const float inv = 1.0f / fmaxf((float)(e - s), 1.0f);
  mean_r[(size_t)w * 64 + lane] = acc * inv;
}

// ---------------- node update: (mean_r @ W + b) * old, LN, residual ----------
// reads nein, writes neout (ping-pong so the pre-update emb gather stays valid)

__launch_bounds__(256)
__global__ void node_update_gemm(
    int N, const float* __restrict__ mean_r, const int* __restrict__ ecnt,
    const float* __restrict__ W, const float* __restrict__ bias,
    const float* __restrict__ g, const float* __restrict__ b,
    const float* __restrict__ nein, float* __restrict__ neout)
{
  __shared__ __align__(16) float lw[64*128];
  __shared__ float lm[32][65];
  const int tid = threadIdx.x;
  const int base = blockIdx.x * 32;

  for (int i = tid; i < 8192; i += 256) lw[i] = W[i];
  {
    const int rr0 = tid >> 6, k = tid & 63;
    for (int rr = rr0; rr < 32; rr += 4) {
      const int n = base + rr;
      lm[rr][k] = (n < N) ? mean_r[(size_t)n*64 + k] : 0.0f;
    }
  }
  __syncthreads();

  const int r0 = (tid >> 5) * 4, j0 = (tid & 31) * 4;
  float acc[4][4];
  #pragma unroll
  for (int j = 0; j < 4; ++j) {
    const float bj = bias[j0 + j];
    acc[0][j] = bj; acc[1][j] = bj; acc[2][j] = bj; acc[3][j] = bj;
  }
  for (int k = 0; k < 64; ++k) {
    const float4 w = *(const float4*)&lw[k*128 + j0];
    const float s0 = lm[r0][k],   s1 = lm[r0+1][k];
    const float s2 = lm[r0+2][k], s3 = lm[r0+3][k];
    acc[0][0] += s0*w.x; acc[0][1] += s0*w.y; acc[0][2] += s0*w.z; acc[0][3] += s0*w.w;
    acc[1][0] += s1*w.x; acc[1][1] += s1*w.y; acc[1][2] += s1*w.z; acc[1][3] += s1*w.w;
    acc[2][0] += s2*w.x; acc[2][1] += s2*w.y; acc[2][2] += s2*w.z; acc[2][3] += s2*w.w;
    acc[3][0] += s3*w.x; acc[3][1] += s3*w.y; acc[3][2] += s3*w.z; acc[3][3] += s3*w.w;
  }

  const float g0 = g[j0], g1 = g[j0+1], g2 = g[j0+2], g3 = g[j0+3];
  const float bb0 = b[j0], bb1 = b[j0+1], bb2 = b[j0+2], bb3 = b[j0+3];
  #pragma unroll
  for (int i = 0; i < 4; ++i) {
    const int n = base + r0 + i;
    if (n >= N) continue;
    const float mask = (ecnt[n] > 0) ? 1.0f : 0.0f;
    const float4 old = *(const float4*)&nein[(size_t)n*128 + j0];
    const float x0 = old.x * acc[i][0] * mask;
    const float x1 = old.y * acc[i][1] * mask;
    const float x2 = old.z * acc[i][2] * mask;
    const float x3 = old.w * acc[i][3] * mask;
    float s = x0 + x1 + x2 + x3;
    float ss = x0*x0 + x1*x1 + x2*x2 + x3*x3;
    #pragma unroll
    for (int o = 1; o <= 16; o <<= 1) {
      s  += __shfl_xor(s, o);
      ss += __shfl_xor(ss, o);
    }
    const float m = s * (1.0f/128.0f);
    const float inv = rsqrtf(ss * (1.0f/128.0f) - m*m + LN_EPS);
    float4 o4;
    o4.x = C_RES*old.x + C_NEW*((x0 - m)*inv*g0 + bb0);
    o4.y = C_RES*old.y + C_NEW*((x1 - m)*inv*g1 + bb1);
    o4.z = C_RES*old.z + C_NEW*((x2 - m)*inv*g2 + bb2);
    o4.w = C_RES*old.w + C_NEW*((x3 - m)*inv*g3 + bb3);
    *(float4*)&neout[(size_t)n*128 + j0] = o4;
  }
}

// ---------------- per-node precompute: nepre = node_emb @ W1a + b1 -----------
// 96 rows/block, 3 waves. W1a = first 32KB (16384 u16, kc 0..7) of packed hid.

__launch_bounds__(192)
__global__ void nepre_mfma(int N, const float* __restrict__ node_emb,
                           const unsigned short* __restrict__ wpackh1,
                           const float* __restrict__ hb1,
                           float* __restrict__ nepre)
{
  __shared__ __align__(16) unsigned short afrag[24*512];  // 24KB
  __shared__ __align__(16) unsigned short wlds[32*512];   // 32KB (kc 0..7 x ct 0..3)
  const int tid = threadIdx.x, lane = tid & 63, wave = tid >> 6;
  const int cl = lane & 31;
  const int base = blockIdx.x * 96;

  for (int i = tid; i < 2048; i += 192)
    *(u16x8*)&wlds[i*8] = *(const u16x8*)&wpackh1[i*8];

  {
    const int r = tid >> 1, h = tid & 1;
    int rowg = base + r;
    if (rowg >= N) rowg = N - 1;
    const float* s = node_emb + (size_t)rowg * 128;
    #pragma unroll
    for (int g = 0; g < 8; ++g) {
      const int k = h*64 + g*8;
      const u16x8 w = cvt8(s + k);
      const int kc = k >> 4;
      const int s_ = (r & 31) + 32*((k >> 3) & 1);
      *(u16x8*)&afrag[(kc*3 + (r>>5))*512 + swz(s_, kc)*8] = w;
    }
  }
  __syncthreads();

  f32x16 acc0, acc1, acc2, acc3;
  {
    const float bv0 = hb1[cl], bv1 = hb1[32+cl];
    const float bv2 = hb1[64+cl], bv3 = hb1[96+cl];
    #pragma unroll
    for (int q = 0; q < 16; ++q) { acc0[q]=bv0; acc1[q]=bv1; acc2[q]=bv2; acc3[q]=bv3; }
  }
  #pragma unroll
  for (int kc = 0; kc < 8; ++kc) {
    const short8 a  = *(const short8*)&afrag[(kc*3 + wave)*512 + swz(lane, kc)*8];
    const short8 w0 = *(const short8*)&wlds[(kc*4 + 0)*512 + lane*8];
    const short8 w1 = *(const short8*)&wlds[(kc*4 + 1)*512 + lane*8];
    const short8 w2 = *(const short8*)&wlds[(kc*4 + 2)*512 + lane*8];
    const short8 w3 = *(const short8*)&wlds[(kc*4 + 3)*512 + lane*8];
    acc0 = __builtin_amdgcn_mfma_f32_32x32x16_bf16(a, w0, acc0, 0, 0, 0);
    acc1 = __builtin_amdgcn_mfma_f32_32x32x16_bf16(a, w1, acc1, 0, 0, 0);
    acc2 = __builtin_amdgcn_mfma_f32_32x32x16_bf16(a, w2, acc2, 0, 0, 0);
    acc3 = __builtin_amdgcn_mfma_f32_32x32x16_bf16(a, w3, acc3, 0, 0, 0);
  }

  #pragma unroll
  for (int q = 0; q < 16; ++q) {
    const int row32 = (q & 3) + 8*(q >> 2) + 4*(lane >> 5);
    const int row   = base + wave*32 + row32;
    if (row >= N) continue;
    float* op = nepre + (size_t)row*128;
    op[cl]    = acc0[q];
    op[32+cl] = acc1[q];
    op[64+cl] = acc2[q];
    op[96+cl] = acc3[q];
  }
}

// ---------------- FUSED (emb)+hidden-MLP+radial-ResNet (merged E|E2) ---------
// FIRST=1 (layer 0): hidden_prev = (radial@embW+embb)*0.5*(ne_old[i0]+ne_old[i1])
// computed in-kernel (A-operand = aR, already loaded) and scattered to afragH;
// no global hidden read. FIRST=0 (layer 1): hidden_prev read from global f32.

#define STAGE_WG(SRC, OFFU16, B) do {                                           \
    _Pragma("unroll")                                                           \
    for (int i_ = 0; i_ < 2; ++i_) {                                            \
      const int c_ = tid + i_*256;                                              \
      *(u16x8*)&wg[B][c_*8] = *(const u16x8*)&(SRC)[(OFFU16) + c_*8];           \
    }                                                                           \
  } while (0)

#define SCATTER_AFRAGH(ACCARR, DOTANH) do {                                     \
    _Pragma("unroll")                                                           \
    for (int ct_ = 0; ct_ < 4; ++ct_) {                                         \
      const int kc_  = ct_*2 + ((lane >> 4) & 1);                               \
      const int oct_ = (lane >> 3) & 1;                                         \
      const int j_   = lane & 7;                                                \
      const int xk_  = (oct_ << 1) ^ ((kc_ & 1) << 2);                          \
      const int hi_  = 4*khalf;                                                 \
      const int bi_  = (wave*8 + kc_)*512 + oct_*256 + j_;                      \
      _Pragma("unroll")                                                         \
      for (int q_ = 0; q_ < 16; ++q_) {                                         \
        const int m32_ = (q_ & 3) + 8*(q_ >> 2) + hi_;                          \
        const float v_ = (DOTANH) ? fast_tanh(ACCARR[ct_][q_]) : ACCARR[ct_][q_];\
        afragH[bi_ + (m32_ ^ xk_)*8] = f2b(v_);                                 \
      }                                                                         \
    }                                                                           \
  } while (0)

template<int FIRST>
__launch_bounds__(256, 3)
__global__ void hidrdl_mfma(
    int g1,
    int n1, const int* __restrict__ idx1, const float* __restrict__ ud1,
    float* __restrict__ hid1, float* __restrict__ rad1,
    int n2, const int* __restrict__ idx2, const float* __restrict__ ud2,
    float* __restrict__ hid2, float* __restrict__ rad2,
    const float* __restrict__ nepre,
    const float* __restrict__ ne_old,           // FIRST only: pre-update node_emb
    const unsigned short* __restrict__ wpackE_, // FIRST only: packed emb W (8192 u16)
    const float* __restrict__ embb,             // FIRST only: emb bias [128]
    const unsigned short* __restrict__ wpackh,
    const float* __restrict__ hb2, const float* __restrict__ hb3,
    const unsigned short* __restrict__ wpackr,
    const float* __restrict__ rb1, const float* __restrict__ rb2,
    const float* __restrict__ rb3,
    const float* __restrict__ eln_g, const float* __restrict__ eln_b)
{
  __shared__ __align__(16) unsigned short afragH[16384];  // 32KB
  __shared__ __align__(16) unsigned short wg[2][4096];    // 16KB

  const int tid  = threadIdx.x;
  const int lane = tid & 63;
  const int wave = tid >> 6;       // rt 0..3
  const int cl   = lane & 31;
  const int khalf = lane >> 5;

  int blk = blockIdx.x;
  int nrows; const int* idx0; const float* ud; float* hidden; float* radial;
  if (blk < g1) { nrows = n1; idx0 = idx1; ud = ud1; hidden = hid1; radial = rad1; }
  else { blk -= g1; nrows = n2; idx0 = idx2; ud = ud2; hidden = hid2; radial = rad2; }
  const int base = blk * 128;

  int lrow = base + wave*32 + cl;
  if (lrow >= nrows) lrow = nrows - 1;
  const float* hsrc = hidden + (size_t)lrow * 128;
  const float* rsrc = radial + (size_t)lrow * 64;

  short8 aR[4];
  #pragma unroll
  for (int kc = 0; kc < 4; ++kc) aR[kc] = cvt8s(rsrc + kc*16 + khalf*8);

  short8 aH[8];
  if (!FIRST) {
    #pragma unroll
    for (int kc = 0; kc < 8; ++kc) aH[kc] = cvt8s(hsrc + kc*16 + khalf*8);
  }

  f32x16 acc[4];

  if (FIRST) {
    // ---- fused emb: acc = radial @ embW + embb ----
    #pragma unroll
    for (int ct = 0; ct < 4; ++ct) {
      const float bv = embb[ct*32 + cl];
      #pragma unroll
      for (int q = 0; q < 16; ++q) acc[ct][q] = bv;
    }
    STAGE_WG(wpackE_, 0, 0);
    __syncthreads();
    STAGE_WG(wpackE_, 4096, 1);
    #pragma unroll
    for (int kcl = 0; kcl < 2; ++kcl) {
      const short8 a = aR[kcl];
      #pragma unroll
      for (int ct = 0; ct < 4; ++ct) {
        const short8 b = *(const short8*)&wg[0][ (kcl*4 + ct)*512 + lane*8 ];
        acc[ct] = __builtin_amdgcn_mfma_f32_32x32x16_bf16(a, b, acc[ct], 0, 0, 0);
      }
    }
    __syncthreads();
    STAGE_WG(wpackh, 16384, 0);   // hid L1 phase-0 weights
    #pragma unroll
    for (int kcl = 0; kcl < 2; ++kcl) {
      const short8 a = aR[2 + kcl];
      #pragma unroll
      for (int ct = 0; ct < 4; ++ct) {
        const short8 b = *(const short8*)&wg[1][ (kcl*4 + ct)*512 + lane*8 ];
        acc[ct] = __builtin_amdgcn_mfma_f32_32x32x16_bf16(a, b, acc[ct], 0, 0, 0);
      }
    }
    // ---- multiply by 0.5*(ne_old[i0]+ne_old[i1]) ----
    #pragma unroll
    for (int q = 0; q < 16; ++q) {
      const int row32 = (q & 3) + 8*(q >> 2) + 4*khalf;
      int row = base + wave*32 + row32;
      if (row >= nrows) row = nrows - 1;
      const int i0 = idx0[row];
      const int i1 = idx0[nrows + row];
      const float* n0 = ne_old + (size_t)i0 * 128;
      const float* n1 = ne_old + (size_t)i1 * 128;
      acc[0][q] *= 0.5f * (n0[cl]      + n1[cl]);
      acc[1][q] *= 0.5f * (n0[32 + cl] + n1[32 + cl]);
      acc[2][q] *= 0.5f * (n0[64 + cl] + n1[64 + cl]);
      acc[3][q] *= 0.5f * (n0[96 + cl] + n1[96 + cl]);
    }
    // ---- scatter hidden_prev (no tanh) -> afragH (wave-local) ----
    SCATTER_AFRAGH(acc, false);
    __syncthreads();   // wg[1] reads done before p-loop overwrites; wg[0] staged
  } else {
    STAGE_WG(wpackh, 16384, 0);
    __syncthreads();
  }

  // ---- acc init: gather nepre[i0[row]] (coalesced 128B half-wave loads) ----
  #pragma unroll
  for (int q = 0; q < 16; ++q) {
    const int row32 = (q & 3) + 8*(q >> 2) + 4*khalf;
    int row = base + wave*32 + row32;
    if (row >= nrows) row = nrows - 1;
    const float* np = nepre + (size_t)idx0[row] * 128;
    acc[0][q] = np[cl];
    acc[1][q] = np[32 + cl];
    acc[2][q] = np[64 + cl];
    acc[3][q] = np[96 + cl];
  }

  // ========= hid layer 1 (hidden half only): K=128, phases 0..3 =========
  #pragma unroll
  for (int p = 0; p < 4; ++p) {
    if (p < 3) STAGE_WG(wpackh, 16384 + (p+1)*4096, (p+1)&1);
    else       STAGE_WG(wpackh, 32768, 0);
    #pragma unroll
    for (int kcl = 0; kcl < 2; ++kcl) {
      const int kc = p*2 + kcl;
      const short8 a = FIRST
        ? *(const short8*)&afragH[ (wave*8 + kc)*512 + swz(lane, kc)*8 ]
        : aH[kc];
      #pragma unroll
      for (int ct = 0; ct < 4; ++ct) {
        const short8 b = *(const short8*)&wg[p&1][ (kcl*4 + ct)*512 + lane*8 ];
        acc[ct] = __builtin_amdgcn_mfma_f32_32x32x16_bf16(a, b, acc[ct], 0, 0, 0);
      }
    }
    __syncthreads();
  }

  // ---- transition 1 (wave-local, tanh) -> afragH ----
  SCATTER_AFRAGH(acc, true);

  // ========= hid layer 2: K=128, phases 4..7 =========
  #pragma unroll
  for (int ct = 0; ct < 4; ++ct) {
    const float bv = hb2[ct*32 + cl];
    #pragma unroll
    for (int q = 0; q < 16; ++q) acc[ct][q] = bv;
  }
  #pragma unroll
  for (int p = 0; p < 4; ++p) {
    if (p < 3) STAGE_WG(wpackh, 32768 + (p+1)*4096, (p+1)&1);
    else       STAGE_WG(wpackh, 49152, 0);
    #pragma unroll
    for (int kcl = 0; kcl < 2; ++kcl) {
      const int kc = p*2 + kcl;
      const short8 a = *(const short8*)&afragH[ (wave*8 + kc)*512 + swz(lane, kc)*8 ];
      #pragma unroll
      for (int ct = 0; ct < 4; ++ct) {
        const short8 b = *(const short8*)&wg[p&1][ (kcl*4 + ct)*512 + lane*8 ];
        acc[ct] = __builtin_amdgcn_mfma_f32_32x32x16_bf16(a, b, acc[ct], 0, 0, 0);
      }
    }
    __syncthreads();
  }

  // ---- transition 2 (wave-local, tanh) -> afragH ----
  SCATTER_AFRAGH(acc, true);

  // ========= hid layer 3: K=128, phases 8..11 =========
  #pragma unroll
  for (int ct = 0; ct < 4; ++ct) {
    const float bv = hb3[ct*32 + cl];
    #pragma unroll
    for (int q = 0; q < 16; ++q) acc[ct][q] = bv;
  }
  #pragma unroll
  for (int p = 0; p < 4; ++p) {
    if (p < 3) STAGE_WG(wpackh, 49152 + (p+1)*4096, (p+1)&1);
    else       STAGE_WG(wpackr, 0, 0);
    #pragma unroll
    for (int kcl = 0; kcl < 2; ++kcl) {
      const int kc = p*2 + kcl;
      const short8 a = *(const short8*)&afragH[ (wave*8 + kc)*512 + swz(lane, kc)*8 ];
      #pragma unroll
      for (int ct = 0; ct < 4; ++ct) {
        const short8 b = *(const short8*)&wg[p&1][ (kcl*4 + ct)*512 + lane*8 ];
        acc[ct] = __builtin_amdgcn_mfma_f32_32x32x16_bf16(a, b, acc[ct], 0, 0, 0);
      }
    }
    __syncthreads();
  }

  // ---- hid epilogue: direct global store + scatter (no tanh) -> afragH ----
  #pragma unroll
  for (int ct = 0; ct < 4; ++ct) {
    const int col = ct*32 + cl;
    #pragma unroll
    for (int q = 0; q < 16; ++q) {
      const int row = base + wave*32 + (q & 3) + 8*(q >> 2) + 4*khalf;
      if (row < nrows) hidden[(size_t)row*128 + col] = acc[ct][q];
    }
  }
  SCATTER_AFRAGH(acc, false);

  // ========= rdl layer 1: K=192 =========
  f32x16 racc0, racc1;
  {
    const float bv0 = rb1[cl], bv1 = rb1[32 + cl];
    #pragma unroll
    for (int q = 0; q < 16; ++q) { racc0[q] = bv0; racc1[q] = bv1; }
  }
  #pragma unroll
  for (int t = 0; t < 3; ++t) {
    if (t < 2) STAGE_WG(wpackr, (t+1)*4096, (t+1)&1);
    else       STAGE_WG(wpackr, 12288, 1);
    #pragma unroll
    for (int kk = 0; kk < 4; ++kk) {
      const int kc = t*4 + kk;
      const short8 a = (kc < 4) ? aR[kc]
        : *(const short8*)&afragH[ (wave*8 + (kc-4))*512 + swz(lane, kc-4)*8 ];
      const short8 w0 = *(const short8*)&wg[t&1][ (kk*2 + 0)*512 + lane*8 ];
      const short8 w1 = *(const short8*)&wg[t&1][ (kk*2 + 1)*512 + lane*8 ];
      racc0 = __builtin_amdgcn_mfma_f32_32x32x16_bf16(a, w0, racc0, 0, 0, 0);
      racc1 = __builtin_amdgcn_mfma_f32_32x32x16_bf16(a, w1, racc1, 0, 0, 0);
    }
    __syncthreads();
  }

  // ---- rdl transition 1 (tanh) -> afragH blocks 0..3 (wave-local) ----
  #pragma unroll
  for (int ct = 0; ct < 2; ++ct) {
    const int colh = ct*32 + cl;
    const int kc2  = colh >> 4;
    const int b3_  = (colh >> 3) & 1;
    const int jj   = colh & 7;
    const int blk2 = (wave*8 + kc2)*512;
    #pragma unroll
    for (int q = 0; q < 16; ++q) {
      const int row32 = (q & 3) + 8*(q >> 2) + 4*khalf;
      const int s_ = (row32 & 31) + 32*b3_;
      const float v = ct ? racc1[q] : racc0[q];
      afragH[blk2 + swz(s_, kc2)*8 + jj] = f2b(fast_tanh(v));
    }
  }

  // ========= rdl layer 2: K=64 (buf 1) =========
  f32x16 rh0, rh1;
  {
    const float bv0 = rb2[cl], bv1 = rb2[32 + cl];
    #pragma unroll
    for (int q = 0; q < 16; ++q) { rh0[q] = bv0; rh1[q] = bv1; }
  }
  STAGE_WG(wpackr, 16384, 0);
  #pragma unroll
  for (int kc = 0; kc < 4; ++kc) {
    const short8 a  = *(const short8*)&afragH[ (wave*8 + kc)*512 + swz(lane, kc)*8 ];
    const short8 w0 = *(const short8*)&wg[1][ (kc*2 + 0)*512 + lane*8 ];
    const short8 w1 = *(const short8*)&wg[1][ (kc*2 + 1)*512 + lane*8 ];
    rh0 = __builtin_amdgcn_mfma_f32_32x32x16_bf16(a, w0, rh0, 0, 0, 0);
    rh1 = __builtin_amdgcn_mfma_f32_32x32x16_bf16(a, w1, rh1, 0, 0, 0);
  }
  __syncthreads();

  // ---- rdl transition 2: tanh(h) -> afragH blocks 4..7 (wave-local) ----
  #pragma unroll
  for (int ct = 0; ct < 2; ++ct) {
    const int colh = ct*32 + cl;
    const int kc2  = colh >> 4;
    const int b3_  = (colh >> 3) & 1;
    const int jj   = colh & 7;
    const int blk2 = (wave*8 + 4 + kc2)*512;
    #pragma unroll
    for (int q = 0; q < 16; ++q) {
      const int row32 = (q & 3) + 8*(q >> 2) + 4*khalf;
      const int s_ = (row32 & 31) + 32*b3_;
      const float v = ct ? rh1[q] : rh0[q];
      afragH[blk2 + swz(s_, kc2)*8 + jj] = f2b(fast_tanh(v));
    }
  }

  // ========= rdl layer 3: K=64 (buf 0) =========
  {
    const float bv0 = rb3[cl], bv1 = rb3[32 + cl];
    #pragma unroll
    for (int q = 0; q < 16; ++q) { racc0[q] = bv0; racc1[q] = bv1; }
  }
  #pragma unroll
  for (int kc = 0; kc < 4; ++kc) {
    const short8 a  = *(const short8*)&afragH[ (wave*8 + 4 + kc)*512 + swz(lane, kc)*8 ];
    const short8 w0 = *(const short8*)&wg[0][ (kc*2 + 0)*512 + lane*8 ];
    const short8 w1 = *(const short8*)&wg[0][ (kc*2 + 1)*512 + lane*8 ];
    racc0 = __builtin_amdgcn_mfma_f32_32x32x16_bf16(a, w0, racc0, 0, 0, 0);
    racc1 = __builtin_amdgcn_mfma_f32_32x32x16_bf16(a, w1, racc1, 0, 0, 0);
  }

  // ---- rdl epilogue: +h, LN (shfl butterfly), residual-scale, direct store --
  const float eg0 = eln_g[cl],      eb0 = eln_b[cl];
  const float eg1 = eln_g[32 + cl], eb1 = eln_b[32 + cl];
  const float* rtile = radial + (size_t)(base + wave*32) * 64;

  #pragma unroll
  for (int q = 0; q < 16; ++q) {
    const float v0 = racc0[q] + rh0[q];
    const float v1 = racc1[q] + rh1[q];
    float s = v0 + v1, ss = v0*v0 + v1*v1;
    #pragma unroll
    for (int o = 1; o <= 16; o <<= 1) {
      s  += __shfl_xor(s, o);
      ss += __shfl_xor(ss, o);
    }
    const float m   = s * (1.0f/64.0f);
    const float inv = rsqrtf(ss * (1.0f/64.0f) - m*m + LN_EPS);
    const int row32 = (q & 3) + 8*(q >> 2) + 4*khalf;
    const int row   = base + wave*32 + row32;
    if (row < nrows) {
      const float u = ud[row];
      const float oldA = rtile[row32*64 + cl];
      const float oldB = rtile[row32*64 + 32 + cl];
      radial[(size_t)row*64 + cl]      = C_RES*oldA + C_NEW*u*((v0 - m)*inv*eg0 + eb0);
      radial[(size_t)row*64 + 32 + cl] = C_RES*oldB + C_NEW*u*((v1 - m)*inv*eg1 + eb1);
    }
  }
}

// ---------------- launch -----------------------------------------------------

extern "C" void kernel_launch(void* const* d_in, const int* in_sizes, int n_in,
                              void* d_out, int out_size, void* d_ws, size_t ws_size,
                              hipStream_t stream)
{
  const int*   atom_types = (const int*)  d_in[0];
  const float* env_vec    = (const float*)d_in[1];
  const float* env_len    = (const float*)d_in[2];
  const float* edge_len   = (const float*)d_in[3];
  const int*   env_idx    = (const int*)  d_in[4];
  const int*   edge_idx   = (const int*)  d_in[5];
  const float* bessel_w   = (const float*)d_in[6];
  const float* srW1 = (const float*)d_in[7];  const float* srb1 = (const float*)d_in[8];
  const float* srW2 = (const float*)d_in[9];  const float* srb2 = (const float*)d_in[10];
  const float* srW3 = (const float*)d_in[11]; const float* srb3 = (const float*)d_in[12];
  const float* rdW1 = (const float*)d_in[13]; const float* rdb1 = (const float*)d_in[14];
  const float* rdW2 = (const float*)d_in[15]; const float* rdb2 = (const float*)d_in[16];
  const float* rdW3 = (const float*)d_in[17]; const float* rdb3 = (const float*)d_in[18];
  const float* ne_emb_W = (const float*)d_in[19]; const float* ne_emb_b = (const float*)d_in[20];
  const float* ne_nln_g = (const float*)d_in[21]; const float* ne_nln_b = (const float*)d_in[22];
  const float* ne_eln_g = (const float*)d_in[23]; const float* ne_eln_b = (const float*)d_in[24];
  const float* ly_emb_W = (const float*)d_in[25]; const float* ly_emb_b = (const float*)d_in[26];
  const float* ly_hid_W1 = (const float*)d_in[27]; const float* ly_hid_b1 = (const float*)d_in[28];
  const float* ly_hid_W2 = (const float*)d_in[29]; const float* ly_hid_b2 = (const float*)d_in[30];
  const float* ly_hid_W3 = (const float*)d_in[31]; const float* ly_hid_b3 = (const float*)d_in[32];
  const float* ly_rdl_W1 = (const float*)d_in[33]; const float* ly_rdl_b1 = (const float*)d_in[34];
  const float* ly_rdl_W2 = (const float*)d_in[35]; const float* ly_rdl_b2 = (const float*)d_in[36];
  const float* ly_rdl_W3 = (const float*)d_in[37]; const float* ly_rdl_b3 = (const float*)d_in[38];
  const float* ly_nln_g = (const float*)d_in[39]; const float* ly_nln_b = (const float*)d_in[40];
  const float* ly_eln_g = (const float*)d_in[41]; const float* ly_eln_b = (const float*)d_in[42];

  const int N  = in_sizes[0];
  const int E  = in_sizes[2];
  const int E2 = in_sizes[3];

  float* out = (float*)d_out;
  float* env_radial  = out;
  float* edge_radial = env_radial + (size_t)E * 64;
  float* node_emb    = edge_radial + (size_t)E2 * 64;
  float* env_hidden  = node_emb + (size_t)N * 128;
  float* edge_hidden = env_hidden + (size_t)E * 128;

  float* ws = (float*)d_ws;
  float* ud_env  = ws;  ws += E;
  float* ud_edge = ws;  ws += E2;
  float* aggS    = ws;  ws += (size_t)N * 48;
  float* msgbuf  = ws;  ws += (size_t)E * 20;   // sval[16] | evud[3] | pad
  // aggS+msgbuf (N*48 + E*20 floats, contiguous) are dead after node_emb_kernel;
  // carve mean_r (N*64) and nemb2 (N*128) out of them -> NO extra ws usage.
  float* mean_r  = aggS;
  float* nemb2   = aggS + (size_t)N * 64;
  float* nepre   = ws;  ws += (size_t)N * 128;  // per-node hid-L1 precompute
  unsigned short* wpack  = (unsigned short*)ws; ws += 65536;   // hid: 2 x 65536 u16
  unsigned short* wpack2 = (unsigned short*)ws; ws += 20480;   // rdl: 2 x 20480 u16
  unsigned short* wpack3 = (unsigned short*)ws; ws += 9216;    // feat: 18432 u16
  unsigned short* wpackE = (unsigned short*)ws; ws += 4096;    // emb: 8192 u16
  int* ecnt = (int*)ws; ws += N;
  int* eoff = (int*)ws; ws += N + 1;
  int* ecur = (int*)ws; ws += N + 1;
  int* perm = (int*)ws; ws += E;

  const int gEr  = (E  + 95) / 96;
  const int gE2r = (E2 + 95) / 96;
  const int gEf  = (E  + 127) / 128;
  const int gE2f = (E2 + 127) / 128;
  const int gN32 = (N + 31) / 32;
  const int gN96 = (N + 95) / 96;
  const int gN4w = (N * 64 + 255) / 256;

  // CSR build over env graph (i1 = env_idx[1])
  zero_int_kernel<<<256, 256, 0, stream>>>(ecnt, N);
  hist_kernel<<<(E + 255) / 256, 256, 0, stream>>>(E, env_idx, ecnt);
  scan_kernel<<<1, 1024, 0, stream>>>(ecnt, eoff, ecur, N);
  scatter_kernel<<<(E + 255) / 256, 256, 0, stream>>>(E, env_idx, ecur, perm);

  pack_hid_weights<<<512, 256, 0, stream>>>(ly_hid_W1, ly_hid_W2, ly_hid_W3, wpack);
  pack_rdl_weights<<<160, 256, 0, stream>>>(ly_rdl_W1, ly_rdl_W2, ly_rdl_W3, wpack2);
  pack_feat_weights<<<72, 256, 0, stream>>>(rdW1, rdW2, rdW3, srW1, srW2, srW3, wpack3);
  pack_emb_weights<<<32, 256, 0, stream>>>(ne_emb_W, wpackE);

  feat_mfma<<<gEr + gE2r, 192, 0, stream>>>(
      gEr, E, env_len, env_idx, env_radial, ud_env,
      E2, edge_len, edge_idx, edge_radial, ud_edge,
      atom_types, env_vec, bessel_w, wpack3,
      srb1, srb2, srb3, rdb1, rdb2, rdb3,
      ne_eln_g, ne_eln_b, msgbuf);

  msg_gather_kernel<<<gN4w, 256, 0, stream>>>(N, eoff, perm, msgbuf, aggS);
  node_emb_kernel<<<N, 128, 0, stream>>>(N, aggS, ecnt, ne_nln_g, ne_nln_b, node_emb);

  // ---- layer 0 ----
  agg_gather_kernel<<<gN4w, 256, 0, stream>>>(N, eoff, perm, env_radial, mean_r);
  node_update_gemm<<<gN32, 256, 0, stream>>>(N, mean_r, ecnt,
      ly_emb_W, ly_emb_b, ly_nln_g, ly_nln_b, node_emb, nemb2);
  nepre_mfma<<<gN96, 192, 0, stream>>>(N, nemb2, wpack, ly_hid_b1, nepre);
  hidrdl_mfma<1><<<gEf + gE2f, 256, 0, stream>>>(
      gEf,
      E, env_idx, ud_env, env_hidden, env_radial,
      E2, edge_idx, ud_edge, edge_hidden, edge_radial,
      nepre,
      node_emb, wpackE, ne_emb_b,   // pre-update node_emb for the fused emb
      wpack, ly_hid_b2, ly_hid_b3,
      wpack2, ly_rdl_b1, ly_rdl_b2, ly_rdl_b3,
      ly_eln_g, ly_eln_b);

  // ---- layer 1 ----
  agg_gather_kernel<<<gN4w, 256, 0, stream>>>(N, eoff, perm, env_radial, mean_r);
  node_update_gemm<<<gN32, 256, 0, stream>>>(N, mean_r, ecnt,
      ly_emb_W + (size_t)64*128, ly_emb_b + 128,
      ly_nln_g + 128, ly_nln_b + 128, nemb2, node_emb);
  nepre_mfma<<<gN96, 192, 0, stream>>>(N, node_emb, wpack + 65536,
      ly_hid_b1 + 128, nepre);
  hidrdl_mfma<0><<<gEf + gE2f, 256, 0, stream>>>(
      gEf,
      E, env_idx, ud_env, env_hidden, env_radial,
      E2, edge_idx, ud_edge, edge_hidden, edge_radial,
      nepre,
      nullptr, nullptr, nullptr,
      wpack + 65536, ly_hid_b2 + 128, ly_hid_b3 + 128,
      wpack2 + 20480, ly_rdl_b1 + 64, ly_rdl_b2 + 64, ly_rdl_b3 + 64,
      ly_eln_g + 64, ly_eln_b + 64);
}

// Round 15
// 1093.765 us; speedup vs baseline: 1.0229x; 1.0229x over previous
//
#include <hip/hip_runtime.h>
#include <math.h>

#define C_RES 0.89442719f
#define C_NEW 0.4472f
#define LN_EPS 1e-5f
#define BESSEL_PREF 0.6324555320336759f  // sqrt(2/5)
#define RC_INV 0.2f

typedef __attribute__((ext_vector_type(8))) short short8;
typedef __attribute__((ext_vector_type(8))) unsigned short u16x8;
typedef __attribute__((ext_vector_type(16))) float f32x16;

// Pade(5,2)-style continued-fraction tanh, input clamped to [-3,3].
__device__ __forceinline__ float fast_tanh(float x) {
  float t = fminf(3.0f, fmaxf(-3.0f, x));
  float t2 = t * t;
  float num = t * fmaf(t2, 10.0f, 105.0f);
  float den = fmaf(t2, fmaf(t2, 1.0f, 45.0f), 105.0f);
  return num * __builtin_amdgcn_rcpf(den);
}

// compiler bf16 cast (RNE) -> hipcc fuses pairs into v_cvt_pk_bf16_f32
__device__ __forceinline__ unsigned short f2b(float f) {
  __bf16 h = (__bf16)f;
  return __builtin_bit_cast(unsigned short, h);
}

__device__ __forceinline__ float b2f(unsigned short v) {
  return __uint_as_float((unsigned)v << 16);
}

__device__ __forceinline__ u16x8 cvt8(const float* s) {
  const float4 v0 = *(const float4*)s;
  const float4 v1 = *(const float4*)(s + 4);
  u16x8 w;
  w[0]=f2b(v0.x); w[1]=f2b(v0.y); w[2]=f2b(v0.z); w[3]=f2b(v0.w);
  w[4]=f2b(v1.x); w[5]=f2b(v1.y); w[6]=f2b(v1.z); w[7]=f2b(v1.w);
  return w;
}

__device__ __forceinline__ short8 cvt8s(const float* s) {
  const float4 v0 = *(const float4*)s;
  const float4 v1 = *(const float4*)(s + 4);
  short8 w;
  w[0]=(short)f2b(v0.x); w[1]=(short)f2b(v0.y); w[2]=(short)f2b(v0.z); w[3]=(short)f2b(v0.w);
  w[4]=(short)f2b(v1.x); w[5]=(short)f2b(v1.y); w[6]=(short)f2b(v1.z); w[7]=(short)f2b(v1.w);
  return w;
}

__device__ __forceinline__ float poly_cutoff(float x) {
  float xr = x * RC_INV;
  if (xr >= 1.0f) return 0.0f;
  float x2 = xr * xr;
  float x3 = x2 * xr;
  float x6 = x3 * x3;
  return 1.0f - 28.0f * x6 + 48.0f * x6 * xr - 21.0f * x6 * x2;
}

// A-frag slot swizzle.
__device__ __forceinline__ int swz(int s, int kc) {
  return s ^ ((s >> 5) << 1) ^ ((kc & 1) << 2);
}

__global__ void zero_int_kernel(int* __restrict__ p, int n) {
  int i = blockIdx.x * blockDim.x + threadIdx.x;
  int stride = gridDim.x * blockDim.x;
  for (; i < n; i += stride) p[i] = 0;
}

// ---------------- CSR build: hist -> scan -> scatter --------------------------

__global__ void hist_kernel(int E, const int* __restrict__ idx, int* __restrict__ ecnt) {
  int t = blockIdx.x * 256 + threadIdx.x;
  if (t < E) atomicAdd(&ecnt[idx[E + t]], 1);
}

__launch_bounds__(1024)
__global__ void scan_kernel(const int* __restrict__ ecnt, int* __restrict__ eoff,
                            int* __restrict__ ecur, int n) {
  __shared__ int wsum[16];
  __shared__ int carry;
  const int tid = threadIdx.x;
  const int lane = tid & 63, wid = tid >> 6;
  if (tid == 0) carry = 0;
  __syncthreads();
  for (int b0 = 0; b0 < n; b0 += 1024) {
    const int i = b0 + tid;
    const int v = (i < n) ? ecnt[i] : 0;
    int incl = v;
    #pragma unroll
    for (int o = 1; o < 64; o <<= 1) {
      const int t = __shfl_up(incl, o);
      if (lane >= o) incl += t;
    }
    if (lane == 63) wsum[wid] = incl;
    __syncthreads();
    if (wid == 0) {
      const int wv = (lane < 16) ? wsum[lane] : 0;
      int wsc = wv;
      #pragma unroll
      for (int o = 1; o < 16; o <<= 1) {
        const int t = __shfl_up(wsc, o);
        if (lane >= o) wsc += t;
      }
      if (lane < 16) wsum[lane] = wsc - wv;  // exclusive
    }
    __syncthreads();
    const int c0 = carry;
    const int excl = c0 + wsum[wid] + incl - v;
    if (i < n) { eoff[i] = excl; ecur[i] = excl; }
    __syncthreads();
    if (tid == 1023) carry = c0 + wsum[15] + incl;
    __syncthreads();
  }
  if (tid == 0) eoff[n] = carry;
}

__global__ void scatter_kernel(int E, const int* __restrict__ idx,
                               int* __restrict__ ecur, int* __restrict__ perm) {
  int t = blockIdx.x * 256 + threadIdx.x;
  if (t < E) {
    const int pos = atomicAdd(&ecur[idx[E + t]], 1);
    perm[pos] = t;
  }
}

// ---------------- weight packers ---------------------------------------------

__global__ void pack_hid_weights(const float* __restrict__ W1,
                                 const float* __restrict__ W2,
                                 const float* __restrict__ W3,
                                 unsigned short* __restrict__ out)
{
  int t = blockIdx.x * 256 + threadIdx.x;  // 0..131071
  if (t >= 131072) return;
  int l = t >> 16;
  int oidx = t & 65535;
  const float* src;
  int midx;
  if (oidx < 32768)      { src = W1 + l * 32768; midx = oidx; }
  else if (oidx < 49152) { src = W2 + l * 16384; midx = oidx - 32768; }
  else                   { src = W3 + l * 16384; midx = oidx - 49152; }
  int j = midx & 7;
  int lane = (midx >> 3) & 63;
  int blk = midx >> 9;
  int ct = blk & 3, kc = blk >> 2;
  int col = ct * 32 + (lane & 31);
  int k = kc * 16 + (lane >> 5) * 8 + j;
  out[l * 65536 + oidx] = f2b(src[k * 128 + col]);
}

__global__ void pack_rdl_weights(const float* __restrict__ W1,
                                 const float* __restrict__ W2,
                                 const float* __restrict__ W3,
                                 unsigned short* __restrict__ out)
{
  int t = blockIdx.x * 256 + threadIdx.x;  // 0..40959
  if (t >= 40960) return;
  int l = t / 20480;
  int o = t - l * 20480;
  const float* src;
  int midx;
  if (o < 12288)      { src = W1 + l * 12288; midx = o; }
  else if (o < 16384) { src = W2 + l * 4096;  midx = o - 12288; }
  else                { src = W3 + l * 4096;  midx = o - 16384; }
  int j = midx & 7;
  int lane = (midx >> 3) & 63;
  int blk = midx >> 9;
  int ct = blk & 1, kc = blk >> 1;
  int col = ct * 32 + (lane & 31);
  int k = kc * 16 + (lane >> 5) * 8 + j;
  out[l * 20480 + o] = f2b(src[k * 64 + col]);
}

__global__ void pack_feat_weights(const float* __restrict__ rdW1,
                                  const float* __restrict__ rdW2,
                                  const float* __restrict__ rdW3,
                                  const float* __restrict__ srW1,
                                  const float* __restrict__ srW2,
                                  const float* __restrict__ srW3,
                                  unsigned short* __restrict__ out)
{
  int t = blockIdx.x * 256 + threadIdx.x;  // 0..18431
  if (t >= 18432) return;
  const int blk = t >> 9, midx = t & 511;
  const int j = midx & 7, lane = (midx >> 3) & 63;
  const float* src; int kc, ct, K, NC;
  if (blk < 4)       { int b = blk;      src = rdW1; kc = b>>1; ct = b&1; K = 24; NC = 64; }
  else if (blk < 12) { int b = blk - 4;  src = rdW2; kc = b>>1; ct = b&1; K = 64; NC = 64; }
  else if (blk < 20) { int b = blk - 12; src = rdW3; kc = b>>1; ct = b&1; K = 64; NC = 64; }
  else if (blk < 24) { int b = blk - 20; src = srW1; kc = b>>1; ct = b&1; K = 24; NC = 64; }
  else if (blk < 32) { int b = blk - 24; src = srW2; kc = b>>1; ct = b&1; K = 64; NC = 64; }
  else               { int b = blk - 32; src = srW3; kc = b;    ct = 0;   K = 64; NC = 16; }
  const int col = ct * 32 + (lane & 31);
  const int k = kc * 16 + (lane >> 5) * 8 + j;
  const float v = (k < K && col < NC) ? src[k * NC + col] : 0.0f;
  out[t] = f2b(v);
}

__global__ void pack_emb_weights(const float* __restrict__ W,
                                 unsigned short* __restrict__ out)
{
  int t = blockIdx.x * 256 + threadIdx.x;  // 0..8191
  if (t >= 8192) return;
  const int j = t & 7, lane = (t >> 3) & 63, blk = t >> 9;
  const int ct = blk & 3, kc = blk >> 2;
  const int col = ct * 32 + (lane & 31);
  const int k = kc * 16 + (lane >> 5) * 8 + j;
  out[t] = f2b(W[k * 128 + col]);
}

// ---------------- stage-A via bf16 MFMA (merged E|E2) ------------------------
// 96 rows/block, 192 threads (3 waves), one barrier.

#define FEAT_TRANS(BASEBLK, V0, V1) do {                                        \
    _Pragma("unroll")                                                           \
    for (int ct_ = 0; ct_ < 2; ++ct_) {                                         \
      const int colh_ = ct_*32 + cl;                                            \
      const int kc2_  = colh_ >> 4;                                             \
      const int b3_   = (colh_ >> 3) & 1;                                       \
      const int jj_   = colh_ & 7;                                              \
      const int blk_  = ((BASEBLK) + kc2_*3 + wave)*512;                        \
      _Pragma("unroll")                                                         \
      for (int q_ = 0; q_ < 16; ++q_) {                                         \
        const int row32_ = (q_ & 3) + 8*(q_ >> 2) + 4*(lane >> 5);              \
        const int s2_ = (row32_ & 31) + 32*b3_;                                 \
        const float v_ = ct_ ? (V1)[q_] : (V0)[q_];                             \
        afrag[blk_ + swz(s2_, kc2_)*8 + jj_] = f2b(fast_tanh(v_));              \
      }                                                                         \
    }                                                                           \
  } while (0)

__launch_bounds__(192)
__global__ void feat_mfma(
    int g1, int n1, const float* __restrict__ lens1, const int* __restrict__ idx1,
    float* __restrict__ radial1, float* __restrict__ ud1,
    int n2, const float* __restrict__ lens2, const int* __restrict__ idx2,
    float* __restrict__ radial2, float* __restrict__ ud2,
    const int* __restrict__ types, const float* __restrict__ vecs,
    const float* __restrict__ bessel_w,
    const unsigned short* __restrict__ wpackf,
    const float* __restrict__ srb1, const float* __restrict__ srb2,
    const float* __restrict__ srb3,
    const float* __restrict__ rdb1, const float* __restrict__ rdb2,
    const float* __restrict__ rdb3,
    const float* __restrict__ eln_g, const float* __restrict__ eln_b,
    float* __restrict__ msgbuf)
{
  __shared__ __align__(16) unsigned short afrag[30*512];  // 30KB
  __shared__ __align__(16) unsigned short wlds[36*512];   // 36KB
  __shared__ float udl[96];

  const int tid  = threadIdx.x;    // 0..191
  const int lane = tid & 63;
  const int wave = tid >> 6;
  const int cl   = lane & 31;

  int blk = blockIdx.x;
  const bool has_sr = (blk < g1);
  int nrows; const float* lens; const int* idx; float* radial_out; float* ud_out;
  if (has_sr) { nrows = n1; lens = lens1; idx = idx1; radial_out = radial1; ud_out = ud1; }
  else { blk -= g1; nrows = n2; lens = lens2; idx = idx2; radial_out = radial2; ud_out = ud2; }
  const int base = blk * 96;

  for (int i = tid; i < 2304; i += 192)
    *(u16x8*)&wlds[i*8] = *(const u16x8*)&wpackf[i*8];

  {
    const int r = tid >> 1, h = tid & 1;
    int rowc = base + r;
    const bool valid = rowc < nrows;
    if (!valid) rowc = nrows - 1;
    const int i0 = idx[rowc];
    const int i1 = idx[nrows + rowc];
    const float len = lens[rowc];
    const float ud = poly_cutoff(len);
    const int t0 = types[i0], t1 = types[i1];
    const float invl = 1.0f / len;
    const int rt = r >> 5;
    #pragma unroll
    for (int m = 0; m < 12; ++m) {
      const int k = h + m*2;
      float v;
      if (k < 4)      v = (t0 == k) ? 1.0f : 0.0f;
      else if (k < 8) v = (t1 == (k-4)) ? 1.0f : 0.0f;
      else            v = ud * BESSEL_PREF * __sinf(bessel_w[k-8] * len * RC_INV) * invl;
      const int kc = k >> 4;
      const int s_ = (r & 31) + 32*((k >> 3) & 1);
      afrag[(kc*3 + rt)*512 + swz(s_, kc)*8 + (k & 7)] = f2b(v);
    }
    #pragma unroll
    for (int m = 0; m < 4; ++m) {
      const int k = 24 + h + m*2;
      const int s_ = (r & 31) + 32*((k >> 3) & 1);
      afrag[(1*3 + rt)*512 + swz(s_, 1)*8 + (k & 7)] = 0;
    }
    if (h == 0) {
      udl[r] = ud;
      if (valid) {
        ud_out[rowc] = ud;
        if (has_sr) {
          msgbuf[(size_t)rowc*20 + 16] = ud * vecs[(size_t)rowc*3 + 0];
          msgbuf[(size_t)rowc*20 + 17] = ud * vecs[(size_t)rowc*3 + 1];
          msgbuf[(size_t)rowc*20 + 18] = ud * vecs[(size_t)rowc*3 + 2];
        }
      }
    }
  }
  __syncthreads();

  f32x16 acc0, acc1;

  // ======== rd path ========
  {
    const float bv0 = rdb1[cl], bv1 = rdb1[32 + cl];
    #pragma unroll
    for (int q = 0; q < 16; ++q) { acc0[q] = bv0; acc1[q] = bv1; }
  }
  #pragma unroll
  for (int kc = 0; kc < 2; ++kc) {
    const short8 a  = *(const short8*)&afrag[(kc*3 + wave)*512 + swz(lane, kc)*8];
    const short8 w0 = *(const short8*)&wlds[(kc*2 + 0)*512 + lane*8];
    const short8 w1 = *(const short8*)&wlds[(kc*2 + 1)*512 + lane*8];
    acc0 = __builtin_amdgcn_mfma_f32_32x32x16_bf16(a, w0, acc0, 0, 0, 0);
    acc1 = __builtin_amdgcn_mfma_f32_32x32x16_bf16(a, w1, acc1, 0, 0, 0);
  }
  FEAT_TRANS(6, acc0, acc1);

  {
    const float bv0 = rdb2[cl], bv1 = rdb2[32 + cl];
    #pragma unroll
    for (int q = 0; q < 16; ++q) { acc0[q] = bv0; acc1[q] = bv1; }
  }
  #pragma unroll
  for (int kc = 0; kc < 4; ++kc) {
    const short8 a  = *(const short8*)&afrag[((6 + kc*3) + wave)*512 + swz(lane, kc)*8];
    const short8 w0 = *(const short8*)&wlds[(4 + kc*2 + 0)*512 + lane*8];
    const short8 w1 = *(const short8*)&wlds[(4 + kc*2 + 1)*512 + lane*8];
    acc0 = __builtin_amdgcn_mfma_f32_32x32x16_bf16(a, w0, acc0, 0, 0, 0);
    acc1 = __builtin_amdgcn_mfma_f32_32x32x16_bf16(a, w1, acc1, 0, 0, 0);
  }
  FEAT_TRANS(18, acc0, acc1);

  {
    const float bv0 = rdb3[cl], bv1 = rdb3[32 + cl];
    #pragma unroll
    for (int q = 0; q < 16; ++q) { acc0[q] = bv0; acc1[q] = bv1; }
  }
  #pragma unroll
  for (int kc = 0; kc < 4; ++kc) {
    const short8 a  = *(const short8*)&afrag[((18 + kc*3) + wave)*512 + swz(lane, kc)*8];
    const short8 w0 = *(const short8*)&wlds[(12 + kc*2 + 0)*512 + lane*8];
    const short8 w1 = *(const short8*)&wlds[(12 + kc*2 + 1)*512 + lane*8];
    acc0 = __builtin_amdgcn_mfma_f32_32x32x16_bf16(a, w0, acc0, 0, 0, 0);
    acc1 = __builtin_amdgcn_mfma_f32_32x32x16_bf16(a, w1, acc1, 0, 0, 0);
  }
  {
    const float eg0 = eln_g[cl],      eb0 = eln_b[cl];
    const float eg1 = eln_g[32 + cl], eb1 = eln_b[32 + cl];
    #pragma unroll
    for (int q = 0; q < 16; ++q) {
      const float v0 = acc0[q], v1 = acc1[q];
      float s = v0 + v1, ss = v0*v0 + v1*v1;
      #pragma unroll
      for (int o = 1; o <= 16; o <<= 1) {
        s  += __shfl_xor(s, o);
        ss += __shfl_xor(ss, o);
      }
      const float m   = s * (1.0f/64.0f);
      const float inv = rsqrtf(ss * (1.0f/64.0f) - m*m + LN_EPS);
      const int row32 = (q & 3) + 8*(q >> 2) + 4*(lane >> 5);
      const int rloc  = wave*32 + row32;
      const int row   = base + rloc;
      if (row < nrows) {
        const float u = udl[rloc];
        radial_out[(size_t)row*64 + cl]      = ((v0 - m)*inv*eg0 + eb0) * u;
        radial_out[(size_t)row*64 + 32 + cl] = ((v1 - m)*inv*eg1 + eb1) * u;
      }
    }
  }

  // ======== sr path ========
  if (has_sr) {
    {
      const float bv0 = srb1[cl], bv1 = srb1[32 + cl];
      #pragma unroll
      for (int q = 0; q < 16; ++q) { acc0[q] = bv0; acc1[q] = bv1; }
    }
    #pragma unroll
    for (int kc = 0; kc < 2; ++kc) {
      const short8 a  = *(const short8*)&afrag[(kc*3 + wave)*512 + swz(lane, kc)*8];
      const short8 w0 = *(const short8*)&wlds[(20 + kc*2 + 0)*512 + lane*8];
      const short8 w1 = *(const short8*)&wlds[(20 + kc*2 + 1)*512 + lane*8];
      acc0 = __builtin_amdgcn_mfma_f32_32x32x16_bf16(a, w0, acc0, 0, 0, 0);
      acc1 = __builtin_amdgcn_mfma_f32_32x32x16_bf16(a, w1, acc1, 0, 0, 0);
    }
    FEAT_TRANS(6, acc0, acc1);

    {
      const float bv0 = srb2[cl], bv1 = srb2[32 + cl];
      #pragma unroll
      for (int q = 0; q < 16; ++q) { acc0[q] = bv0; acc1[q] = bv1; }
    }
    #pragma unroll
    for (int kc = 0; kc < 4; ++kc) {
      const short8 a  = *(const short8*)&afrag[((6 + kc*3) + wave)*512 + swz(lane, kc)*8];
      const short8 w0 = *(const short8*)&wlds[(24 + kc*2 + 0)*512 + lane*8];
      const short8 w1 = *(const short8*)&wlds[(24 + kc*2 + 1)*512 + lane*8];
      acc0 = __builtin_amdgcn_mfma_f32_32x32x16_bf16(a, w0, acc0, 0, 0, 0);
      acc1 = __builtin_amdgcn_mfma_f32_32x32x16_bf16(a, w1, acc1, 0, 0, 0);
    }
    FEAT_TRANS(18, acc0, acc1);

    {
      const float bv0 = (cl < 16) ? srb3[cl] : 0.0f;
      #pragma unroll
      for (int q = 0; q < 16; ++q) acc0[q] = bv0;
    }
    #pragma unroll
    for (int kc = 0; kc < 4; ++kc) {
      const short8 a  = *(const short8*)&afrag[((18 + kc*3) + wave)*512 + swz(lane, kc)*8];
      const short8 w0 = *(const short8*)&wlds[(32 + kc)*512 + lane*8];
      acc0 = __builtin_amdgcn_mfma_f32_32x32x16_bf16(a, w0, acc0, 0, 0, 0);
    }
    if (cl < 16) {
      #pragma unroll
      for (int q = 0; q < 16; ++q) {
        const int row32 = (q & 3) + 8*(q >> 2) + 4*(lane >> 5);
        const int rloc  = wave*32 + row32;
        const int row   = base + rloc;
        if (row < nrows) msgbuf[(size_t)row*20 + cl] = acc0[q] * udl[rloc];
      }
    }
  }
}

// ---------------- SE(2) message gather: aggS (no atomics) --------------------

__launch_bounds__(256)
__global__ void msg_gather_kernel(int N, const int* __restrict__ eoff,
                                  const int* __restrict__ perm,
                                  const float* __restrict__ msgbuf,
                                  float* __restrict__ aggS)
{
  const int w = (blockIdx.x * 256 + threadIdx.x) >> 6;
  const int lane = threadIdx.x & 63;
  if (w >= N) return;
  const int s = eoff[w], e = eoff[w + 1];
  const int d = lane / 3, c = lane - d * 3;
  float acc = 0.0f;
  for (int j = s; j < e; ++j) {
    const int ed = perm[j];
    if (lane < 48)
      acc += msgbuf[(size_t)ed*20 + d] * msgbuf[(size_t)ed*20 + 16 + c];
  }
  if (lane < 48) aggS[(size_t)w*48 + lane] = acc;
}

// ---------------- node embedding (gram + LN) ---------------------------------

__device__ __forceinline__ void block128_stats(float x, float& m, float& inv, float* red) {
  float s = x, ss = x*x;
  #pragma unroll
  for (int o = 32; o; o >>= 1) { s += __shfl_down(s, o); ss += __shfl_down(ss, o); }
  const int t = threadIdx.x;
  if ((t & 63) == 0) { red[(t >> 6)*2] = s; red[(t >> 6)*2 + 1] = ss; }
  __syncthreads();
  const float S = red[0] + red[2], SS = red[1] + red[3];
  m = S * (1.0f/128.0f);
  const float var = SS * (1.0f/128.0f) - m*m;
  inv = rsqrtf(var + LN_EPS);
}

__launch_bounds__(128)
__global__ void node_emb_kernel(int N, const float* __restrict__ aggS,
                                const int* __restrict__ ecnt,
                                const float* __restrict__ g, const float* __restrict__ b,
                                float* __restrict__ node_emb)
{
  const int n = blockIdx.x, t = threadIdx.x;
  __shared__ float S[48];
  __shared__ float red[4];
  if (t < 48) S[t] = aggS[(size_t)n*48 + t];
  __syncthreads();
  const float ic = 1.0f / fmaxf((float)ecnt[n], 1.0f);
  const int d = t >> 3, e = t & 7;
  const float x = (S[d*3+0]*S[e*3+0] + S[d*3+1]*S[e*3+1] + S[d*3+2]*S[e*3+2]) * ic * ic;
  float m, inv;
  block128_stats(x, m, inv, red);
  node_emb[(size_t)n*128 + t] = (x - m)*inv*g[t] + b[t];
}

// ---------------- per-layer aggregation: CSR gather (no atomics) -------------

__launch_bounds__(256)
__global__ void agg_gather_kernel(int N, const int* __restrict__ eoff,
                                  const int* __restrict__ perm,
                                  const float* __restrict__ radial,
                                  float* __restrict__ mean_r)
{
  const int w = (blockIdx.x * 256 + threadIdx.x) >> 6;
  const int lane = threadIdx.x & 63;
  if (w >= N) return;
  const int s = eoff[w], e = eoff[w + 1];
  float acc = 0.0f;
  for (int j = s; j < e; ++j) {
    const int ed = perm[j];
    acc += radial[(size_t)ed * 64 + lane];
  }
  const float inv = 1.0f / fmaxf((float)(e - s), 1.0f);
  mean_r[(size_t)w * 64 + lane] = acc * inv;
}

// ---------------- node update: (mean_r @ W + b) * old, LN, residual ----------

__launch_bounds__(256)
__global__ void node_update_gemm(
    int N, const float* __restrict__ mean_r, const int* __restrict__ ecnt,
    const float* __restrict__ W, const float* __restrict__ bias,
    const float* __restrict__ g, const float* __restrict__ b,
    float* __restrict__ node_emb)
{
  __shared__ __align__(16) float lw[64*128];
  __shared__ float lm[32][65];
  const int tid = threadIdx.x;
  const int base = blockIdx.x * 32;

  for (int i = tid; i < 8192; i += 256) lw[i] = W[i];
  {
    const int rr0 = tid >> 6, k = tid & 63;
    for (int rr = rr0; rr < 32; rr += 4) {
      const int n = base + rr;
      lm[rr][k] = (n < N) ? mean_r[(size_t)n*64 + k] : 0.0f;
    }
  }
  __syncthreads();

  const int r0 = (tid >> 5) * 4, j0 = (tid & 31) * 4;
  float acc[4][4];
  #pragma unroll
  for (int j = 0; j < 4; ++j) {
    const float bj = bias[j0 + j];
    acc[0][j] = bj; acc[1][j] = bj; acc[2][j] = bj; acc[3][j] = bj;
  }
  for (int k = 0; k < 64; ++k) {
    const float4 w = *(const float4*)&lw[k*128 + j0];
    const float s0 = lm[r0][k],   s1 = lm[r0+1][k];
    const float s2 = lm[r0+2][k], s3 = lm[r0+3][k];
    acc[0][0] += s0*w.x; acc[0][1] += s0*w.y; acc[0][2] += s0*w.z; acc[0][3] += s0*w.w;
    acc[1][0] += s1*w.x; acc[1][1] += s1*w.y; acc[1][2] += s1*w.z; acc[1][3] += s1*w.w;
    acc[2][0] += s2*w.x; acc[2][1] += s2*w.y; acc[2][2] += s2*w.z; acc[2][3] += s2*w.w;
    acc[3][0] += s3*w.x; acc[3][1] += s3*w.y; acc[3][2] += s3*w.z; acc[3][3] += s3*w.w;
  }

  const float g0 = g[j0], g1 = g[j0+1], g2 = g[j0+2], g3 = g[j0+3];
  const float bb0 = b[j0], bb1 = b[j0+1], bb2 = b[j0+2], bb3 = b[j0+3];
  #pragma unroll
  for (int i = 0; i < 4; ++i) {
    const int n = base + r0 + i;
    if (n >= N) continue;
    const float mask = (ecnt[n] > 0) ? 1.0f : 0.0f;
    const float4 old = *(const float4*)&node_emb[(size_t)n*128 + j0];
    const float x0 = old.x * acc[i][0] * mask;
    const float x1 = old.y * acc[i][1] * mask;
    const float x2 = old.z * acc[i][2] * mask;
    const float x3 = old.w * acc[i][3] * mask;
    float s = x0 + x1 + x2 + x3;
    float ss = x0*x0 + x1*x1 + x2*x2 + x3*x3;
    #pragma unroll
    for (int o = 1; o <= 16; o <<= 1) {
      s  += __shfl_xor(s, o);
      ss += __shfl_xor(ss, o);
    }
    const float m = s * (1.0f/128.0f);
    const float inv = rsqrtf(ss * (1.0f/128.0f) - m*m + LN_EPS);
    float4 o4;
    o4.x = C_RES*old.x + C_NEW*((x0 - m)*inv*g0 + bb0);
    o4.y = C_RES*old.y + C_NEW*((x1 - m)*inv*g1 + bb1);
    o4.z = C_RES*old.z + C_NEW*((x2 - m)*inv*g2 + bb2);
    o4.w = C_RES*old.w + C_NEW*((x3 - m)*inv*g3 + bb3);
    *(float4*)&node_emb[(size_t)n*128 + j0] = o4;
  }
}

// ---------------- embedding GEMM via MFMA (merged E|E2) ----------------------

__launch_bounds__(192)
__global__ void emb_mfma(
    int g1, int n1, const float* __restrict__ radial1, const int* __restrict__ idx1,
    float* __restrict__ out1,
    int n2, const float* __restrict__ radial2, const int* __restrict__ idx2,
    float* __restrict__ out2,
    const unsigned short* __restrict__ wpck, const float* __restrict__ bias,
    const float* __restrict__ node_emb)
{
  __shared__ __align__(16) unsigned short afrag[12*512];  // 12KB
  __shared__ __align__(16) unsigned short wlds[16*512];   // 16KB
  __shared__ int i0l[96], i1l[96];

  const int tid = threadIdx.x, lane = tid & 63, wave = tid >> 6;
  const int cl = lane & 31;

  int blk = blockIdx.x;
  int nrows; const float* radial; const int* idx; float* out;
  if (blk < g1) { nrows = n1; radial = radial1; idx = idx1; out = out1; }
  else { blk -= g1; nrows = n2; radial = radial2; idx = idx2; out = out2; }
  const int base = blk * 96;

  for (int i = tid; i < 1024; i += 192)
    *(u16x8*)&wlds[i*8] = *(const u16x8*)&wpck[i*8];

  {
    const int r = tid >> 1, h = tid & 1;
    int rowg = base + r;
    if (rowg >= nrows) rowg = nrows - 1;
    if (h == 0) { i0l[r] = idx[rowg]; i1l[r] = idx[nrows + rowg]; }
    const float* rsrc = radial + (size_t)rowg * 64;
    #pragma unroll
    for (int g = 0; g < 4; ++g) {
      const int k = h*32 + g*8;
      const u16x8 w = cvt8(rsrc + k);
      const int kc = k >> 4;
      const int s_ = (r & 31) + 32*((k >> 3) & 1);
      *(u16x8*)&afrag[(kc*3 + (r>>5))*512 + swz(s_, kc)*8] = w;
    }
  }
  __syncthreads();

  f32x16 acc0, acc1, acc2, acc3;
  {
    const float bv0 = bias[cl], bv1 = bias[32+cl];
    const float bv2 = bias[64+cl], bv3 = bias[96+cl];
    #pragma unroll
    for (int q = 0; q < 16; ++q) { acc0[q]=bv0; acc1[q]=bv1; acc2[q]=bv2; acc3[q]=bv3; }
  }
  #pragma unroll
  for (int kc = 0; kc < 4; ++kc) {
    const short8 a  = *(const short8*)&afrag[(kc*3 + wave)*512 + swz(lane, kc)*8];
    const short8 w0 = *(const short8*)&wlds[(kc*4 + 0)*512 + lane*8];
    const short8 w1 = *(const short8*)&wlds[(kc*4 + 1)*512 + lane*8];
    const short8 w2 = *(const short8*)&wlds[(kc*4 + 2)*512 + lane*8];
    const short8 w3 = *(const short8*)&wlds[(kc*4 + 3)*512 + lane*8];
    acc0 = __builtin_amdgcn_mfma_f32_32x32x16_bf16(a, w0, acc0, 0, 0, 0);
    acc1 = __builtin_amdgcn_mfma_f32_32x32x16_bf16(a, w1, acc1, 0, 0, 0);
    acc2 = __builtin_amdgcn_mfma_f32_32x32x16_bf16(a, w2, acc2, 0, 0, 0);
    acc3 = __builtin_amdgcn_mfma_f32_32x32x16_bf16(a, w3, acc3, 0, 0, 0);
  }

  #pragma unroll
  for (int q = 0; q < 16; ++q) {
    const int row32 = (q & 3) + 8*(q >> 2) + 4*(lane >> 5);
    const int rloc  = wave*32 + row32;
    const int row   = base + rloc;
    if (row >= nrows) continue;
    const float* n0 = node_emb + (size_t)i0l[rloc]*128;
    const float* n1 = node_emb + (size_t)i1l[rloc]*128;
    float* op = out + (size_t)row*128;
    op[cl]    = acc0[q] * 0.5f * (n0[cl]    + n1[cl]);
    op[32+cl] = acc1[q] * 0.5f * (n0[32+cl] + n1[32+cl]);
    op[64+cl] = acc2[q] * 0.5f * (n0[64+cl] + n1[64+cl]);
    op[96+cl] = acc3[q] * 0.5f * (n0[96+cl] + n1[96+cl]);
  }
}

// ---------------- per-node precompute: nepre = node_emb @ W1a + b1 -----------
// 96 rows/block, 3 waves. W1a = first 32KB (16384 u16, kc 0..7) of packed hid.

__launch_bounds__(192)
__global__ void nepre_mfma(int N, const float* __restrict__ node_emb,
                           const unsigned short* __restrict__ wpackh1,
                           const float* __restrict__ hb1,
                           float* __restrict__ nepre)
{
  __shared__ __align__(16) unsigned short afrag[24*512];  // 24KB
  __shared__ __align__(16) unsigned short wlds[32*512];   // 32KB (kc 0..7 x ct 0..3)
  const int tid = threadIdx.x, lane = tid & 63, wave = tid >> 6;
  const int cl = lane & 31;
  const int base = blockIdx.x * 96;

  for (int i = tid; i < 2048; i += 192)
    *(u16x8*)&wlds[i*8] = *(const u16x8*)&wpackh1[i*8];

  {
    const int r = tid >> 1, h = tid & 1;
    int rowg = base + r;
    if (rowg >= N) rowg = N - 1;
    const float* s = node_emb + (size_t)rowg * 128;
    #pragma unroll
    for (int g = 0; g < 8; ++g) {
      const int k = h*64 + g*8;
      const u16x8 w = cvt8(s + k);
      const int kc = k >> 4;
      const int s_ = (r & 31) + 32*((k >> 3) & 1);
      *(u16x8*)&afrag[(kc*3 + (r>>5))*512 + swz(s_, kc)*8] = w;
    }
  }
  __syncthreads();

  f32x16 acc0, acc1, acc2, acc3;
  {
    const float bv0 = hb1[cl], bv1 = hb1[32+cl];
    const float bv2 = hb1[64+cl], bv3 = hb1[96+cl];
    #pragma unroll
    for (int q = 0; q < 16; ++q) { acc0[q]=bv0; acc1[q]=bv1; acc2[q]=bv2; acc3[q]=bv3; }
  }
  #pragma unroll
  for (int kc = 0; kc < 8; ++kc) {
    const short8 a  = *(const short8*)&afrag[(kc*3 + wave)*512 + swz(lane, kc)*8];
    const short8 w0 = *(const short8*)&wlds[(kc*4 + 0)*512 + lane*8];
    const short8 w1 = *(const short8*)&wlds[(kc*4 + 1)*512 + lane*8];
    const short8 w2 = *(const short8*)&wlds[(kc*4 + 2)*512 + lane*8];
    const short8 w3 = *(const short8*)&wlds[(kc*4 + 3)*512 + lane*8];
    acc0 = __builtin_amdgcn_mfma_f32_32x32x16_bf16(a, w0, acc0, 0, 0, 0);
    acc1 = __builtin_amdgcn_mfma_f32_32x32x16_bf16(a, w1, acc1, 0, 0, 0);
    acc2 = __builtin_amdgcn_mfma_f32_32x32x16_bf16(a, w2, acc2, 0, 0, 0);
    acc3 = __builtin_amdgcn_mfma_f32_32x32x16_bf16(a, w3, acc3, 0, 0, 0);
  }

  #pragma unroll
  for (int q = 0; q < 16; ++q) {
    const int row32 = (q & 3) + 8*(q >> 2) + 4*(lane >> 5);
    const int row   = base + wave*32 + row32;
    if (row >= N) continue;
    float* op = nepre + (size_t)row*128;
    op[cl]    = acc0[q];
    op[32+cl] = acc1[q];
    op[64+cl] = acc2[q];
    op[96+cl] = acc3[q];
  }
}

// ---------------- FUSED hidden-MLP + radial-ResNet (merged E|E2) -------------
// 128 rows/block, 256 threads (4 waves). hid layer-1's node_emb half is
// pre-folded into nepre[i0] (per-node); accumulators init by gathering it.

#define STAGE_WG(SRC, OFFU16, B) do {                                           \
    _Pragma("unroll")                                                           \
    for (int i_ = 0; i_ < 2; ++i_) {                                            \
      const int c_ = tid + i_*256;                                              \
      *(u16x8*)&wg[B][c_*8] = *(const u16x8*)&(SRC)[(OFFU16) + c_*8];           \
    }                                                                           \
  } while (0)

__launch_bounds__(256, 3)
__global__ void hidrdl_mfma(
    int g1,
    int n1, const int* __restrict__ idx1, const float* __restrict__ ud1,
    float* __restrict__ hid1, float* __restrict__ rad1,
    int n2, const int* __restrict__ idx2, const float* __restrict__ ud2,
    float* __restrict__ hid2, float* __restrict__ rad2,
    const float* __restrict__ nepre,
    const unsigned short* __restrict__ wpackh,
    const float* __restrict__ hb2, const float* __restrict__ hb3,
    const unsigned short* __restrict__ wpackr,
    const float* __restrict__ rb1, const float* __restrict__ rb2,
    const float* __restrict__ rb3,
    const float* __restrict__ eln_g, const float* __restrict__ eln_b)
{
  __shared__ __align__(16) unsigned short afragH[16384];  // 32KB
  __shared__ __align__(16) unsigned short wg[2][4096];    // 16KB

  const int tid  = threadIdx.x;
  const int lane = tid & 63;
  const int wave = tid >> 6;       // rt 0..3
  const int cl   = lane & 31;
  const int khalf = lane >> 5;

  int blk = blockIdx.x;
  int nrows; const int* idx0; const float* ud; float* hidden; float* radial;
  if (blk < g1) { nrows = n1; idx0 = idx1; ud = ud1; hidden = hid1; radial = rad1; }
  else { blk -= g1; nrows = n2; idx0 = idx2; ud = ud2; hidden = hid2; radial = rad2; }
  const int base = blk * 128;

  int lrow = base + wave*32 + cl;
  if (lrow >= nrows) lrow = nrows - 1;
  const float* hsrc = hidden + (size_t)lrow * 128;
  const float* rsrc = radial + (size_t)lrow * 64;

  short8 aH[8];
  #pragma unroll
  for (int kc = 0; kc < 8; ++kc) aH[kc] = cvt8s(hsrc + kc*16 + khalf*8);

  f32x16 acc[4];

  // ---- acc init: gather nepre[i0[row]] (coalesced 128B half-wave loads) ----
  #pragma unroll
  for (int q = 0; q < 16; ++q) {
    const int row32 = (q & 3) + 8*(q >> 2) + 4*khalf;
    int row = base + wave*32 + row32;
    if (row >= nrows) row = nrows - 1;
    const float* np = nepre + (size_t)idx0[row] * 128;
    acc[0][q] = np[cl];
    acc[1][q] = np[32 + cl];
    acc[2][q] = np[64 + cl];
    acc[3][q] = np[96 + cl];
  }

  // ========= hid layer 1 (hidden half only): K=128, phases 0..3 =========
  STAGE_WG(wpackh, 16384, 0);
  __syncthreads();
  #pragma unroll
  for (int p = 0; p < 4; ++p) {
    if (p < 3) STAGE_WG(wpackh, 16384 + (p+1)*4096, (p+1)&1);
    else       STAGE_WG(wpackh, 32768, 0);
    #pragma unroll
    for (int kcl = 0; kcl < 2; ++kcl) {
      const int kc = p*2 + kcl;
      const short8 a = aH[kc];
      #pragma unroll
      for (int ct = 0; ct < 4; ++ct) {
        const short8 b = *(const short8*)&wg[p&1][ (kcl*4 + ct)*512 + lane*8 ];
        acc[ct] = __builtin_amdgcn_mfma_f32_32x32x16_bf16(a, b, acc[ct], 0, 0, 0);
      }
    }
    __syncthreads();
  }

  // ---- transition 1 (wave-local, tanh) -> afragH ----
  #pragma unroll
  for (int ct = 0; ct < 4; ++ct) {
    const int kc  = ct*2 + ((lane >> 4) & 1);
    const int oct = (lane >> 3) & 1;
    const int j   = lane & 7;
    const int xk  = (oct << 1) ^ ((kc & 1) << 2);
    const int hi  = 4*khalf;
    const int bi  = (wave*8 + kc)*512 + oct*256 + j;
    #pragma unroll
    for (int q = 0; q < 16; ++q) {
      const int m32 = (q & 3) + 8*(q >> 2) + hi;
      afragH[bi + (m32 ^ xk)*8] = f2b(fast_tanh(acc[ct][q]));
    }
  }

  // ========= hid layer 2: K=128, phases 4..7 =========
  #pragma unroll
  for (int ct = 0; ct < 4; ++ct) {
    const float bv = hb2[ct*32 + cl];
    #pragma unroll
    for (int q = 0; q < 16; ++q) acc[ct][q] = bv;
  }
  #pragma unroll
  for (int p = 0; p < 4; ++p) {
    if (p < 3) STAGE_WG(wpackh, 32768 + (p+1)*4096, (p+1)&1);
    else       STAGE_WG(wpackh, 49152, 0);
    #pragma unroll
    for (int kcl = 0; kcl < 2; ++kcl) {
      const int kc = p*2 + kcl;
      const short8 a = *(const short8*)&afragH[ (wave*8 + kc)*512 + swz(lane, kc)*8 ];
      #pragma unroll
      for (int ct = 0; ct < 4; ++ct) {
        const short8 b = *(const short8*)&wg[p&1][ (kcl*4 + ct)*512 + lane*8 ];
        acc[ct] = __builtin_amdgcn_mfma_f32_32x32x16_bf16(a, b, acc[ct], 0, 0, 0);
      }
    }
    __syncthreads();
  }

  // ---- transition 2 (wave-local, tanh) -> afragH ----
  #pragma unroll
  for (int ct = 0; ct < 4; ++ct) {
    const int kc  = ct*2 + ((lane >> 4) & 1);
    const int oct = (lane >> 3) & 1;
    const int j   = lane & 7;
    const int xk  = (oct << 1) ^ ((kc & 1) << 2);
    const int hi  = 4*khalf;
    const int bi  = (wave*8 + kc)*512 + oct*256 + j;
    #pragma unroll
    for (int q = 0; q < 16; ++q) {
      const int m32 = (q & 3) + 8*(q >> 2) + hi;
      afragH[bi + (m32 ^ xk)*8] = f2b(fast_tanh(acc[ct][q]));
    }
  }

  // ========= hid layer 3: K=128, phases 8..11 =========
  #pragma unroll
  for (int ct = 0; ct < 4; ++ct) {
    const float bv = hb3[ct*32 + cl];
    #pragma unroll
    for (int q = 0; q < 16; ++q) acc[ct][q] = bv;
  }
  #pragma unroll
  for (int p = 0; p < 4; ++p) {
    if (p < 3) STAGE_WG(wpackh, 49152 + (p+1)*4096, (p+1)&1);
    else       STAGE_WG(wpackr, 0, 0);
    #pragma unroll
    for (int kcl = 0; kcl < 2; ++kcl) {
      const int kc = p*2 + kcl;
      const short8 a = *(const short8*)&afragH[ (wave*8 + kc)*512 + swz(lane, kc)*8 ];
      #pragma unroll
      for (int ct = 0; ct < 4; ++ct) {
        const short8 b = *(const short8*)&wg[p&1][ (kcl*4 + ct)*512 + lane*8 ];
        acc[ct] = __builtin_amdgcn_mfma_f32_32x32x16_bf16(a, b, acc[ct], 0, 0, 0);
      }
    }
    __syncthreads();
  }

  // ---- hid epilogue: direct global store + scatter (no tanh) -> afragH ----
  #pragma unroll
  for (int ct = 0; ct < 4; ++ct) {
    const int col = ct*32 + cl;
    #pragma unroll
    for (int q = 0; q < 16; ++q) {
      const int row = base + wave*32 + (q & 3) + 8*(q >> 2) + 4*khalf;
      if (row < nrows) hidden[(size_t)row*128 + col] = acc[ct][q];
    }
  }
  #pragma unroll
  for (int ct = 0; ct < 4; ++ct) {
    const int kc  = ct*2 + ((lane >> 4) & 1);
    const int oct = (lane >> 3) & 1;
    const int j   = lane & 7;
    const int xk  = (oct << 1) ^ ((kc & 1) << 2);
    const int hi  = 4*khalf;
    const int bi  = (wave*8 + kc)*512 + oct*256 + j;
    #pragma unroll
    for (int q = 0; q < 16; ++q) {
      const int m32 = (q & 3) + 8*(q >> 2) + hi;
      afragH[bi + (m32 ^ xk)*8] = f2b(acc[ct][q]);
    }
  }

  short8 aR[4];
  #pragma unroll
  for (int kc = 0; kc < 4; ++kc) aR[kc] = cvt8s(rsrc + kc*16 + khalf*8);

  // ========= rdl layer 1: K=192 =========
  f32x16 racc0, racc1;
  {
    const float bv0 = rb1[cl], bv1 = rb1[32 + cl];
    #pragma unroll
    for (int q = 0; q < 16; ++q) { racc0[q] = bv0; racc1[q] = bv1; }
  }
  #pragma unroll
  for (int t = 0; t < 3; ++t) {
    if (t < 2) STAGE_WG(wpackr, (t+1)*4096, (t+1)&1);
    else       STAGE_WG(wpackr, 12288, 1);
    #pragma unroll
    for (int kk = 0; kk < 4; ++kk) {
      const int kc = t*4 + kk;
      const short8 a = (kc < 4) ? aR[kc]
        : *(const short8*)&afragH[ (wave*8 + (kc-4))*512 + swz(lane, kc-4)*8 ];
      const short8 w0 = *(const short8*)&wg[t&1][ (kk*2 + 0)*512 + lane*8 ];
      const short8 w1 = *(const short8*)&wg[t&1][ (kk*2 + 1)*512 + lane*8 ];
      racc0 = __builtin_amdgcn_mfma_f32_32x32x16_bf16(a, w0, racc0, 0, 0, 0);
      racc1 = __builtin_amdgcn_mfma_f32_32x32x16_bf16(a, w1, racc1, 0, 0, 0);
    }
    __syncthreads();
  }

  // ---- rdl transition 1 (tanh) -> afragH blocks 0..3 (wave-local) ----
  #pragma unroll
  for (int ct = 0; ct < 2; ++ct) {
    const int colh = ct*32 + cl;
    const int kc2  = colh >> 4;
    const int b3_  = (colh >> 3) & 1;
    const int jj   = colh & 7;
    const int blk2 = (wave*8 + kc2)*512;
    #pragma unroll
    for (int q = 0; q < 16; ++q) {
      const int row32 = (q & 3) + 8*(q >> 2) + 4*khalf;
      const int s_ = (row32 & 31) + 32*b3_;
      const float v = ct ? racc1[q] : racc0[q];
      afragH[blk2 + swz(s_, kc2)*8 + jj] = f2b(fast_tanh(v));
    }
  }

  // ========= rdl layer 2: K=64 (buf 1) =========
  f32x16 rh0, rh1;
  {
    const float bv0 = rb2[cl], bv1 = rb2[32 + cl];
    #pragma unroll
    for (int q = 0; q < 16; ++q) { rh0[q] = bv0; rh1[q] = bv1; }
  }
  STAGE_WG(wpackr, 16384, 0);
  #pragma unroll
  for (int kc = 0; kc < 4; ++kc) {
    const short8 a  = *(const short8*)&afragH[ (wave*8 + kc)*512 + swz(lane, kc)*8 ];
    const short8 w0 = *(const short8*)&wg[1][ (kc*2 + 0)*512 + lane*8 ];
    const short8 w1 = *(const short8*)&wg[1][ (kc*2 + 1)*512 + lane*8 ];
    rh0 = __builtin_amdgcn_mfma_f32_32x32x16_bf16(a, w0, rh0, 0, 0, 0);
    rh1 = __builtin_amdgcn_mfma_f32_32x32x16_bf16(a, w1, rh1, 0, 0, 0);
  }
  __syncthreads();

  // ---- rdl transition 2: tanh(h) -> afragH blocks 4..7 (wave-local) ----
  #pragma unroll
  for (int ct = 0; ct < 2; ++ct) {
    const int colh = ct*32 + cl;
    const int kc2  = colh >> 4;
    const int b3_  = (colh >> 3) & 1;
    const int jj   = colh & 7;
    const int blk2 = (wave*8 + 4 + kc2)*512;
    #pragma unroll
    for (int q = 0; q < 16; ++q) {
      const int row32 = (q & 3) + 8*(q >> 2) + 4*khalf;
      const int s_ = (row32 & 31) + 32*b3_;
      const float v = ct ? rh1[q] : rh0[q];
      afragH[blk2 + swz(s_, kc2)*8 + jj] = f2b(fast_tanh(v));
    }
  }

  // ========= rdl layer 3: K=64 (buf 0) =========
  {
    const float bv0 = rb3[cl], bv1 = rb3[32 + cl];
    #pragma unroll
    for (int q = 0; q < 16; ++q) { racc0[q] = bv0; racc1[q] = bv1; }
  }
  #pragma unroll
  for (int kc = 0; kc < 4; ++kc) {
    const short8 a  = *(const short8*)&afragH[ (wave*8 + 4 + kc)*512 + swz(lane, kc)*8 ];
    const short8 w0 = *(const short8*)&wg[0][ (kc*2 + 0)*512 + lane*8 ];
    const short8 w1 = *(const short8*)&wg[0][ (kc*2 + 1)*512 + lane*8 ];
    racc0 = __builtin_amdgcn_mfma_f32_32x32x16_bf16(a, w0, racc0, 0, 0, 0);
    racc1 = __builtin_amdgcn_mfma_f32_32x32x16_bf16(a, w1, racc1, 0, 0, 0);
  }

  // ---- rdl epilogue: +h, LN (shfl butterfly), residual-scale, direct store --
  const float eg0 = eln_g[cl],      eb0 = eln_b[cl];
  const float eg1 = eln_g[32 + cl], eb1 = eln_b[32 + cl];
  const float* rtile = radial + (size_t)(base + wave*32) * 64;

  #pragma unroll
  for (int q = 0; q < 16; ++q) {
    const float v0 = racc0[q] + rh0[q];
    const float v1 = racc1[q] + rh1[q];
    float s = v0 + v1, ss = v0*v0 + v1*v1;
    #pragma unroll
    for (int o = 1; o <= 16; o <<= 1) {
      s  += __shfl_xor(s, o);
      ss += __shfl_xor(ss, o);
    }
    const float m   = s * (1.0f/64.0f);
    const float inv = rsqrtf(ss * (1.0f/64.0f) - m*m + LN_EPS);
    const int row32 = (q & 3) + 8*(q >> 2) + 4*khalf;
    const int row   = base + wave*32 + row32;
    if (row < nrows) {
      const float u = ud[row];
      const float oldA = rtile[row32*64 + cl];
      const float oldB = rtile[row32*64 + 32 + cl];
      radial[(size_t)row*64 + cl]      = C_RES*oldA + C_NEW*u*((v0 - m)*inv*eg0 + eb0);
      radial[(size_t)row*64 + 32 + cl] = C_RES*oldB + C_NEW*u*((v1 - m)*inv*eg1 + eb1);
    }
  }
}

// ---------------- launch -----------------------------------------------------

extern "C" void kernel_launch(void* const* d_in, const int* in_sizes, int n_in,
                              void* d_out, int out_size, void* d_ws, size_t ws_size,
                              hipStream_t stream)
{
  const int*   atom_types = (const int*)  d_in[0];
  const float* env_vec    = (const float*)d_in[1];
  const float* env_len    = (const float*)d_in[2];
  const float* edge_len   = (const float*)d_in[3];
  const int*   env_idx    = (const int*)  d_in[4];
  const int*   edge_idx   = (const int*)  d_in[5];
  const float* bessel_w   = (const float*)d_in[6];
  const float* srW1 = (const float*)d_in[7];  const float* srb1 = (const float*)d_in[8];
  const float* srW2 = (const float*)d_in[9];  const float* srb2 = (const float*)d_in[10];
  const float* srW3 = (const float*)d_in[11]; const float* srb3 = (const float*)d_in[12];
  const float* rdW1 = (const float*)d_in[13]; const float* rdb1 = (const float*)d_in[14];
  const float* rdW2 = (const float*)d_in[15]; const float* rdb2 = (const float*)d_in[16];
  const float* rdW3 = (const float*)d_in[17]; const float* rdb3 = (const float*)d_in[18];
  const float* ne_emb_W = (const float*)d_in[19]; const float* ne_emb_b = (const float*)d_in[20];
  const float* ne_nln_g = (const float*)d_in[21]; const float* ne_nln_b = (const float*)d_in[22];
  const float* ne_eln_g = (const float*)d_in[23]; const float* ne_eln_b = (const float*)d_in[24];
  const float* ly_emb_W = (const float*)d_in[25]; const float* ly_emb_b = (const float*)d_in[26];
  const float* ly_hid_W1 = (const float*)d_in[27]; const float* ly_hid_b1 = (const float*)d_in[28];
  const float* ly_hid_W2 = (const float*)d_in[29]; const float* ly_hid_b2 = (const float*)d_in[30];
  const float* ly_hid_W3 = (const float*)d_in[31]; const float* ly_hid_b3 = (const float*)d_in[32];
  const float* ly_rdl_W1 = (const float*)d_in[33]; const float* ly_rdl_b1 = (const float*)d_in[34];
  const float* ly_rdl_W2 = (const float*)d_in[35]; const float* ly_rdl_b2 = (const float*)d_in[36];
  const float* ly_rdl_W3 = (const float*)d_in[37]; const float* ly_rdl_b3 = (const float*)d_in[38];
  const float* ly_nln_g = (const float*)d_in[39]; const float* ly_nln_b = (const float*)d_in[40];
  const float* ly_eln_g = (const float*)d_in[41]; const float* ly_eln_b = (const float*)d_in[42];

  const int N  = in_sizes[0];
  const int E  = in_sizes[2];
  const int E2 = in_sizes[3];

  float* out = (float*)d_out;
  float* env_radial  = out;
  float* edge_radial = env_radial + (size_t)E * 64;
  float* node_emb    = edge_radial + (size_t)E2 * 64;
  float* env_hidden  = node_emb + (size_t)N * 128;
  float* edge_hidden = env_hidden + (size_t)E * 128;

  float* ws = (float*)d_ws;
  float* ud_env  = ws;  ws += E;
  float* ud_edge = ws;  ws += E2;
  float* aggS    = ws;  ws += (size_t)N * 48;
  float* msgbuf  = ws;  ws += (size_t)E * 20;   // sval[16] | evud[3] | pad
  float* mean_r  = msgbuf;                      // reuse after msg_gather
  float* nepre   = ws;  ws += (size_t)N * 128;  // per-node hid-L1 precompute
  unsigned short* wpack  = (unsigned short*)ws; ws += 65536;   // hid: 2 x 65536 u16
  unsigned short* wpack2 = (unsigned short*)ws; ws += 20480;   // rdl: 2 x 20480 u16
  unsigned short* wpack3 = (unsigned short*)ws; ws += 9216;    // feat: 18432 u16
  unsigned short* wpackE = (unsigned short*)ws; ws += 4096;    // emb: 8192 u16
  int* ecnt = (int*)ws; ws += N;
  int* eoff = (int*)ws; ws += N + 1;
  int* ecur = (int*)ws; ws += N + 1;
  int* perm = (int*)ws; ws += E;

  const int gEr  = (E  + 95) / 96;
  const int gE2r = (E2 + 95) / 96;
  const int gEf  = (E  + 127) / 128;
  const int gE2f = (E2 + 127) / 128;
  const int gN32 = (N + 31) / 32;
  const int gN96 = (N + 95) / 96;
  const int gN4w = (N * 64 + 255) / 256;

  // CSR build over env graph (i1 = env_idx[1])
  zero_int_kernel<<<256, 256, 0, stream>>>(ecnt, N);
  hist_kernel<<<(E + 255) / 256, 256, 0, stream>>>(E, env_idx, ecnt);
  scan_kernel<<<1, 1024, 0, stream>>>(ecnt, eoff, ecur, N);
  scatter_kernel<<<(E + 255) / 256, 256, 0, stream>>>(E, env_idx, ecur, perm);

  pack_hid_weights<<<512, 256, 0, stream>>>(ly_hid_W1, ly_hid_W2, ly_hid_W3, wpack);
  pack_rdl_weights<<<160, 256, 0, stream>>>(ly_rdl_W1, ly_rdl_W2, ly_rdl_W3, wpack2);
  pack_feat_weights<<<72, 256, 0, stream>>>(rdW1, rdW2, rdW3, srW1, srW2, srW3, wpack3);
  pack_emb_weights<<<32, 256, 0, stream>>>(ne_emb_W, wpackE);

  feat_mfma<<<gEr + gE2r, 192, 0, stream>>>(
      gEr, E, env_len, env_idx, env_radial, ud_env,
      E2, edge_len, edge_idx, edge_radial, ud_edge,
      atom_types, env_vec, bessel_w, wpack3,
      srb1, srb2, srb3, rdb1, rdb2, rdb3,
      ne_eln_g, ne_eln_b, msgbuf);

  msg_gather_kernel<<<gN4w, 256, 0, stream>>>(N, eoff, perm, msgbuf, aggS);
  node_emb_kernel<<<N, 128, 0, stream>>>(N, aggS, ecnt, ne_nln_g, ne_nln_b, node_emb);

  emb_mfma<<<gEr + gE2r, 192, 0, stream>>>(
      gEr, E, env_radial, env_idx, env_hidden,
      E2, edge_radial, edge_idx, edge_hidden,
      wpackE, ne_emb_b, node_emb);

  for (int l = 0; l < 2; ++l) {
    agg_gather_kernel<<<gN4w, 256, 0, stream>>>(N, eoff, perm, env_radial, mean_r);
    node_update_gemm<<<gN32, 256, 0, stream>>>(N, mean_r, ecnt,
        ly_emb_W + (size_t)l*64*128, ly_emb_b + (size_t)l*128,
        ly_nln_g + (size_t)l*128, ly_nln_b + (size_t)l*128, node_emb);

    nepre_mfma<<<gN96, 192, 0, stream>>>(N, node_emb,
        wpack + (size_t)l*65536, ly_hid_b1 + (size_t)l*128, nepre);

    hidrdl_mfma<<<gEf + gE2f, 256, 0, stream>>>(
        gEf,
        E, env_idx, ud_env, env_hidden, env_radial,
        E2, edge_idx, ud_edge, edge_hidden, edge_radial,
        nepre,
        wpack + (size_t)l*65536,
        ly_hid_b2 + (size_t)l*128, ly_hid_b3 + (size_t)l*128,
        wpack2 + (size_t)l*20480,
        ly_rdl_b1 + (size_t)l*64, ly_rdl_b2 + (size_t)l*64, ly_rdl_b3 + (size_t)l*64,
        ly_eln_g + (size_t)l*64, ly_eln_b + (size_t)l*64);
  }
}